// Round 13
// baseline (172.139 us; speedup 1.0000x reference)
//
#include <hip/hip_runtime.h>

typedef __bf16 bf16x8 __attribute__((ext_vector_type(8)));
typedef float f32x4 __attribute__((ext_vector_type(4)));
typedef unsigned short us4 __attribute__((ext_vector_type(4)));

__device__ __forceinline__ unsigned short f2bf(float f) {
  unsigned int u = __builtin_bit_cast(unsigned int, f);
  u += 0x7fffu + ((u >> 16) & 1u);
  return (unsigned short)(u >> 16);
}
__device__ __forceinline__ float bf2f(unsigned short s) {
  unsigned int u = ((unsigned int)s) << 16;
  return __builtin_bit_cast(float, u);
}
__device__ __forceinline__ f32x4 mfma16(bf16x8 a, bf16x8 b, f32x4 c) {
  return __builtin_amdgcn_mfma_f32_16x16x32_bf16(a, b, c, 0, 0, 0);
}
__device__ __forceinline__ void gload16(const void* g, void* l) {
  __builtin_amdgcn_global_load_lds(
      (const __attribute__((address_space(1))) unsigned int*)g,
      (__attribute__((address_space(3))) unsigned int*)l, 16, 0, 0);
}
__device__ __forceinline__ float fexp2(float x) {
  float r;
  asm("v_exp_f32 %0, %1" : "=v"(r) : "v"(x));
  return r;
}
template <int CTRL>
__device__ __forceinline__ float dppf(float x) {
  return __builtin_bit_cast(
      float, __builtin_amdgcn_mov_dpp(__builtin_bit_cast(int, x), CTRL, 0xf, 0xf, true));
}
__device__ __forceinline__ float rmax16(float x) {
  x = fmaxf(x, dppf<0xB1>(x));
  x = fmaxf(x, dppf<0x4E>(x));
  x = fmaxf(x, dppf<0x124>(x));
  x = fmaxf(x, dppf<0x128>(x));
  return x;
}
__device__ __forceinline__ float rsum16(float x) {
  x += dppf<0xB1>(x);
  x += dppf<0x4E>(x);
  x += dppf<0x124>(x);
  x += dppf<0x128>(x);
  return x;
}

#define QSCL 0.18033688011112042f  /* 0.125 * log2(e) */
#define LOG2E 1.4426950408889634f
#define DEFER_THR 11.5f            /* 8 * log2(e) — defer-rescale threshold */

// ---------------- fused preprocessing: casts + weight transposes + segmask, one launch ----------------
__global__ __launch_bounds__(256) void pre_kernel(
    const float* __restrict__ h, const float* __restrict__ r, const float* __restrict__ wo,
    const float* __restrict__ w0, const float* __restrict__ w1,
    const float* __restrict__ w2, const float* __restrict__ w3,
    const unsigned char* __restrict__ seg, const float* __restrict__ mask,
    unsigned short* __restrict__ hb, unsigned short* __restrict__ rb,
    unsigned short* __restrict__ wo_b,
    unsigned short* __restrict__ o0, unsigned short* __restrict__ o1,
    unsigned short* __restrict__ o2, unsigned short* __restrict__ o3,
    unsigned int* __restrict__ segout) {
  __shared__ float t[32][33];
  const int bx = blockIdx.x;
  const int tid = threadIdx.x;
  if (bx < 7168) {
    int idx = bx * 256 + tid;
    const float* in;
    unsigned short* out;
    int o;
    if (idx < 524288) { in = h; out = hb; o = idx; }
    else if (idx < 1572864) { in = r; out = rb; o = idx - 524288; }
    else { in = wo; out = wo_b; o = idx - 1572864; }
    float4 v = ((const float4*)in)[o];
    us4 tt;
    tt[0] = f2bf(v.x); tt[1] = f2bf(v.y); tt[2] = f2bf(v.z); tt[3] = f2bf(v.w);
    *(us4*)&out[o * 4] = tt;
  } else if (bx < 11264) {
    int zz = bx - 7168;
    int z = zz >> 10, tt_ = zz & 1023;
    const float* in = z == 0 ? w0 : (z == 1 ? w1 : (z == 2 ? w2 : w3));
    unsigned short* out = z == 0 ? o0 : (z == 1 ? o1 : (z == 2 ? o2 : o3));
    int k0 = (tt_ >> 5) * 32;
    int n0 = (tt_ & 31) * 32;
    int rr = tid >> 5;
    int c = tid & 31;
#pragma unroll
    for (int s = 0; s < 4; ++s)
      t[rr + s * 8][c] = in[(k0 + rr + s * 8) * 1024 + n0 + c];
    __syncthreads();
#pragma unroll
    for (int s = 0; s < 4; ++s)
      out[(n0 + rr + s * 8) * 1024 + k0 + c] = f2bf(t[c][rr + s * 8]);
  } else {
    int ij = (bx - 11264) * 256 + tid;
    unsigned short sv = *(const unsigned short*)&seg[ij * 2];
    float2 mv = *(const float2*)&mask[(size_t)ij * 2];
    unsigned int q0 = ((unsigned int)f2bf(mv.x * -1.4426950408889634e30f) << 16) |
                      ((sv & 0xffu) ? 0x3f80u : 0u);
    unsigned int q1 = ((unsigned int)f2bf(mv.y * -1.4426950408889634e30f) << 16) |
                      ((sv >> 8) ? 0x3f80u : 0u);
    segout[ij] = q0;
    segout[1048576 + ij] = q1;
  }
}

// ---------------- all 4 projections (R7 structure) + fused dv epilogue ----------------
__global__ __launch_bounds__(512) void proj4_kernel(
    const unsigned short* __restrict__ hb, const unsigned short* __restrict__ rb,
    const unsigned short* __restrict__ wq_t, const unsigned short* __restrict__ wk_t,
    const unsigned short* __restrict__ wv_t, const unsigned short* __restrict__ wr_t,
    const float* __restrict__ rwb, const float* __restrict__ rrb, const float* __restrict__ rsb,
    const float* __restrict__ seg_embed,
    unsigned short* __restrict__ qwb, unsigned short* __restrict__ qrb,
    unsigned short* __restrict__ khb, unsigned short* __restrict__ vhb,
    unsigned short* __restrict__ krhb,
    float* __restrict__ dvb) {
  __shared__ unsigned short sA[2][128 * 64];
  __shared__ unsigned short sB[2][128 * 64];
  const int bx = blockIdx.x;
  int sel, rblk;
  const unsigned short* A;
  if (bx < 384) { sel = bx >> 7; rblk = bx & 127; A = hb; }
  else { sel = 3; rblk = bx - 384; A = rb; }
  const unsigned short* Bt = sel == 0 ? wq_t : (sel == 1 ? wk_t : (sel == 2 ? wv_t : wr_t));
  const int n0 = (rblk & 7) * 128, m0 = (rblk >> 3) * 128;
  const int tid = threadIdx.x, lane = tid & 63, w = tid >> 6;
  const int wm = w >> 1, wn = w & 1, g = lane >> 4, lc = lane & 15;

  f32x4 acc[2][4] = {};

  auto STAGE = [&](int buf, int kt) {
#pragma unroll
    for (int s = 0; s < 2; ++s) {
      int c = s * 512 + tid;
      int row = c >> 3;
      int ko = ((c & 7) ^ (row & 7)) * 8;
      int lbase = (s * 512 + w * 64) * 8;
      gload16(&A[(size_t)(m0 + row) * 1024 + kt + ko], &sA[buf][lbase]);
      gload16(&Bt[(size_t)(n0 + row) * 1024 + kt + ko], &sB[buf][lbase]);
    }
  };

  STAGE(0, 0);
  __syncthreads();

  for (int kt = 0; kt < 1024; kt += 64) {
    const int cur = (kt >> 6) & 1;
    if (kt < 960) STAGE(cur ^ 1, kt + 64);
    bf16x8 af[2][2], bfr[4][2];
#pragma unroll
    for (int ks = 0; ks < 2; ++ks) {
#pragma unroll
      for (int mi = 0; mi < 2; ++mi) {
        int ra = wm * 32 + mi * 16 + lc;
        af[mi][ks] = *(const bf16x8*)&sA[cur][ra * 64 + (((ks * 4 + g) ^ (ra & 7)) * 8)];
      }
#pragma unroll
      for (int ni = 0; ni < 4; ++ni) {
        int rb_ = wn * 64 + ni * 16 + lc;
        bfr[ni][ks] = *(const bf16x8*)&sB[cur][rb_ * 64 + (((ks * 4 + g) ^ (rb_ & 7)) * 8)];
      }
    }
#pragma unroll
    for (int ks = 0; ks < 2; ++ks)
#pragma unroll
      for (int mi = 0; mi < 2; ++mi)
#pragma unroll
        for (int ni = 0; ni < 4; ++ni)
          acc[mi][ni] = mfma16(af[mi][ks], bfr[ni][ks], acc[mi][ni]);
    __syncthreads();
  }

  if (sel == 0) {
    const int hn = (n0 >> 6) + wn;
    float sedv[4], bwv[4], brv[4], bsv[4];
#pragma unroll
    for (int ni = 0; ni < 4; ++ni) {
      int col = n0 + wn * 64 + ni * 16 + lc;
      sedv[ni] = seg_embed[1024 + hn * 64 + ni * 16 + lc] - seg_embed[hn * 64 + ni * 16 + lc];
      bwv[ni] = rwb[col];
      brv[ni] = rrb[col];
      bsv[ni] = rsb[col];
    }
#pragma unroll
    for (int mi = 0; mi < 2; ++mi) {
      int rowb = m0 + wm * 32 + mi * 16 + g * 4;
#pragma unroll
      for (int r = 0; r < 4; ++r) {
        float e = 0.f;
#pragma unroll
        for (int ni = 0; ni < 4; ++ni) {
          int col = n0 + wn * 64 + ni * 16 + lc;
          float v = acc[mi][ni][r];
          size_t idx = (size_t)(rowb + r) * 1024 + col;
          qwb[idx] = f2bf((v + bwv[ni]) * QSCL);
          qrb[idx] = f2bf((v + brv[ni]) * QSCL);
          e += (v + bsv[ni]) * 0.125f * sedv[ni];
        }
        e = rsum16(e);
        if (lc == 0) {
          int ib = rowb + r;
          int i = ib >> 1, b = ib & 1;
          dvb[(b * 16 + hn) * 1024 + i] = e * LOG2E;
        }
      }
    }
  } else {
#pragma unroll
    for (int ni = 0; ni < 4; ++ni) {
      int col = n0 + wn * 64 + ni * 16 + lc;
#pragma unroll
      for (int mi = 0; mi < 2; ++mi) {
        int rowb = m0 + wm * 32 + mi * 16 + g * 4;
#pragma unroll
        for (int r = 0; r < 4; ++r) {
          float v = acc[mi][ni][r];
          size_t idx = (size_t)(rowb + r) * 1024 + col;
          if (sel == 1) khb[idx] = f2bf(v);
          else if (sel == 2) vhb[idx] = f2bf(v);
          else krhb[idx] = f2bf(v);
        }
      }
    }
  }
}

// ---------------- out-projection: 64x128 tile, 8 waves, BK=64, 2-phase dbuf, swizzled ----------------
__global__ __launch_bounds__(512) void gemm64_out(const unsigned short* __restrict__ A,
                                                  const unsigned short* __restrict__ Bt,
                                                  float* __restrict__ C) {
  __shared__ unsigned short sA[2][64 * 64];
  __shared__ unsigned short sB[2][128 * 64];
  const int tid = threadIdx.x, lane = tid & 63, w = tid >> 6;
  const int wm = w >> 2, wn = w & 3, g = lane >> 4, lc = lane & 15;
  const int m0 = blockIdx.y * 64, n0 = blockIdx.x * 128;
  f32x4 acc[2][2] = {};

  auto STAGE = [&](int buf, int kt) {
    {
      int c = tid;
      int row = c >> 3;
      int ko = ((c & 7) ^ (row & 7)) * 8;
      gload16(&A[(size_t)(m0 + row) * 1024 + kt + ko], &sA[buf][w * 64 * 8]);
    }
#pragma unroll
    for (int s = 0; s < 2; ++s) {
      int c = s * 512 + tid;
      int row = c >> 3;
      int ko = ((c & 7) ^ (row & 7)) * 8;
      gload16(&Bt[(size_t)(n0 + row) * 1024 + kt + ko], &sB[buf][(s * 512 + w * 64) * 8]);
    }
  };

  STAGE(0, 0);
  __syncthreads();

  for (int kt = 0; kt < 1024; kt += 64) {
    const int cur = (kt >> 6) & 1;
    if (kt < 960) STAGE(cur ^ 1, kt + 64);
    bf16x8 af[2][2], bfr[2][2];
#pragma unroll
    for (int ks = 0; ks < 2; ++ks) {
#pragma unroll
      for (int mi = 0; mi < 2; ++mi) {
        int ra = wm * 32 + mi * 16 + lc;
        af[mi][ks] = *(const bf16x8*)&sA[cur][ra * 64 + (((ks * 4 + g) ^ (ra & 7)) * 8)];
      }
#pragma unroll
      for (int ni = 0; ni < 2; ++ni) {
        int rb_ = wn * 32 + ni * 16 + lc;
        bfr[ni][ks] = *(const bf16x8*)&sB[cur][rb_ * 64 + (((ks * 4 + g) ^ (rb_ & 7)) * 8)];
      }
    }
#pragma unroll
    for (int ks = 0; ks < 2; ++ks)
#pragma unroll
      for (int mi = 0; mi < 2; ++mi)
#pragma unroll
        for (int ni = 0; ni < 2; ++ni)
          acc[mi][ni] = mfma16(af[mi][ks], bfr[ni][ks], acc[mi][ni]);
    __syncthreads();
  }
#pragma unroll
  for (int ni = 0; ni < 2; ++ni) {
    int col = n0 + wn * 32 + ni * 16 + lc;
#pragma unroll
    for (int mi = 0; mi < 2; ++mi) {
      int rowb = m0 + wm * 32 + mi * 16 + g * 4;
#pragma unroll
      for (int r = 0; r < 4; ++r)
        C[(size_t)(rowb + r) * 1024 + col] = acc[mi][ni][r];
    }
  }
}

// ---------------- V transpose ----------------
__global__ __launch_bounds__(256) void transpose_v(const unsigned short* __restrict__ vh,
                                                   unsigned short* __restrict__ vT) {
  __shared__ unsigned short t[64][65];
  const int bn = blockIdx.y, j0 = blockIdx.x * 64;
  const int b = bn >> 4, n = bn & 15;
  const int r = threadIdx.x >> 4;
  const int c4 = (threadIdx.x & 15) * 4;
#pragma unroll
  for (int s = 0; s < 4; ++s) {
    int j = r + s * 16;
    us4 v = *(const us4*)&vh[((size_t)(j0 + j) * 2 + b) * 1024 + n * 64 + c4];
    t[j][c4 + 0] = v[0]; t[j][c4 + 1] = v[1]; t[j][c4 + 2] = v[2]; t[j][c4 + 3] = v[3];
  }
  __syncthreads();
#pragma unroll
  for (int s = 0; s < 4; ++s) {
    int d = r + s * 16;
    us4 v;
    v[0] = t[c4 + 0][d]; v[1] = t[c4 + 1][d]; v[2] = t[c4 + 2][d]; v[3] = t[c4 + 3][d];
    *(us4*)&vT[((size_t)bn * 64 + d) * 1024 + j0 + c4] = v;
  }
}

// ---------------- fused relative attention: R12 structure + T13 defer + T5 setprio + bf16 part ----------------
__global__ __launch_bounds__(512, 4) void attn_kernel(
    const unsigned short* __restrict__ qw, const unsigned short* __restrict__ qr,
    const unsigned short* __restrict__ kh, const unsigned short* __restrict__ krh,
    const unsigned short* __restrict__ vT,
    const float* __restrict__ dvb,
    const unsigned int* __restrict__ segmask,
    unsigned short* __restrict__ part, float* __restrict__ ml) {
  __shared__ unsigned short sK[64][72];
  __shared__ unsigned short sVT[64][72];
  __shared__ unsigned short sKR[256][72];  // circular band, slot = jr & 255
  __shared__ unsigned short sP[8][16][80];

  const int tid = threadIdx.x, lane = tid & 63, w = tid >> 6;
  const int g = lane >> 4, lc = lane & 15;
  const int bn = blockIdx.x, b = bn >> 4, n = bn & 15;
  const int i0 = blockIdx.y * 128;
  const int js = blockIdx.z;
  const int S0 = 1024 + js * 512 - i0 - 127;

  bf16x8 fqw[2], fqr[2];
  const int qrow = i0 + w * 16 + lc;
#pragma unroll
  for (int ks = 0; ks < 2; ++ks) {
    size_t off = ((size_t)qrow * 2 + b) * 1024 + n * 64 + ks * 32 + g * 8;
    fqw[ks] = *(const bf16x8*)&qw[off];
    fqr[ks] = *(const bf16x8*)&qr[off];
  }
  float dv[4];
  unsigned int smoff[4];
#pragma unroll
  for (int r = 0; r < 4; ++r) {
    int i = i0 + w * 16 + g * 4 + r;
    dv[r] = dvb[bn * 1024 + i];
    smoff[r] = ((unsigned)b << 20) | ((unsigned)i << 10) | (unsigned)lc;
  }
  float mrun[4], lsum[4];
  f32x4 accO[4] = {};
#pragma unroll
  for (int r = 0; r < 4; ++r) { mrun[r] = -3e38f; lsum[r] = 0.f; }

  const int srow = tid >> 3;
  const int sko = (tid & 7) * 8;

#pragma unroll
  for (int pp = 0; pp < 3; ++pp) {
    int jr = S0 + pp * 64 + srow;
    *(uint4*)&sKR[jr & 255][sko] =
        *(const uint4*)&krh[((size_t)jr * 2 + b) * 1024 + n * 64 + sko];
  }
  int j0 = js * 512;
  uint4 rK = *(const uint4*)&kh[((size_t)(j0 + srow) * 2 + b) * 1024 + n * 64 + sko];
  uint4 rV = *(const uint4*)&vT[((size_t)bn * 64 + srow) * 1024 + j0 + sko];
  uint4 rR = *(const uint4*)&krh[((size_t)(S0 + 192 + srow) * 2 + b) * 1024 + n * 64 + sko];

  for (int t = 0; t < 8; ++t) {
    j0 = (js * 8 + t) * 64;
    __syncthreads();
    *(uint4*)&sK[srow][sko] = rK;
    *(uint4*)&sVT[srow][sko] = rV;
    if (t < 7) {
      *(uint4*)&sKR[(S0 + 192 + t * 64 + srow) & 255][sko] = rR;
      int j0n = j0 + 64;
      rK = *(const uint4*)&kh[((size_t)(j0n + srow) * 2 + b) * 1024 + n * 64 + sko];
      rV = *(const uint4*)&vT[((size_t)bn * 64 + srow) * 1024 + j0n + sko];
      if (t < 6) {
        int jr = S0 + 256 + t * 64 + srow;
        if (jr > 2047) jr = 2047;
        rR = *(const uint4*)&krh[((size_t)jr * 2 + b) * 1024 + n * 64 + sko];
      }
    }
    unsigned int msv[4][4];
#pragma unroll
    for (int r = 0; r < 4; ++r)
#pragma unroll
      for (int nf = 0; nf < 4; ++nf)
        msv[r][nf] = segmask[smoff[r] + j0 + nf * 16];
    __syncthreads();

    const int base = S0 + t * 64 + (7 - w) * 16;
    f32x4 bdk[5];
    __builtin_amdgcn_s_setprio(1);
#pragma unroll
    for (int k = 0; k < 5; ++k) {
      f32x4 a = {0.f, 0.f, 0.f, 0.f};
#pragma unroll
      for (int ks = 0; ks < 2; ++ks) {
        bf16x8 fk = *(const bf16x8*)&sKR[(base + k * 16 + lc) & 255][ks * 32 + g * 8];
        a = mfma16(fqr[ks], fk, a);
      }
      bdk[k] = a;
    }
    __builtin_amdgcn_s_setprio(0);
    float p[4][4];
#pragma unroll
    for (int r = 0; r < 4; ++r) {
      const int a_ = g * 4 + r;
      const int srcl = (lane & 48) | ((lc + 15 - a_) & 15);
      float s0 = __shfl(bdk[0][r], srcl);
      float s1 = __shfl(bdk[1][r], srcl);
      float s2 = __shfl(bdk[2][r], srcl);
      float s3 = __shfl(bdk[3][r], srcl);
      float s4 = __shfl(bdk[4][r], srcl);
      const bool lo = lc <= a_;
#pragma unroll
      for (int nf = 0; nf < 4; ++nf) {
        unsigned int u = msv[r][nf];
        float sgd = (u & 0xffffu) ? dv[r] : 0.f;
        float mkv = bf2f((unsigned short)(u >> 16));
        float bdv = lo ? (nf == 0 ? s0 : nf == 1 ? s1 : nf == 2 ? s2 : s3)
                       : (nf == 0 ? s1 : nf == 1 ? s2 : nf == 2 ? s3 : s4);
        p[r][nf] = sgd + mkv + bdv;
      }
    }
    f32x4 aa[4];
    __builtin_amdgcn_s_setprio(1);
#pragma unroll
    for (int nf = 0; nf < 4; ++nf) {
      f32x4 a = {0.f, 0.f, 0.f, 0.f};
#pragma unroll
      for (int ks = 0; ks < 2; ++ks) {
        bf16x8 fk = *(const bf16x8*)&sK[nf * 16 + lc][ks * 32 + g * 8];
        a = mfma16(fqw[ks], fk, a);
      }
      aa[nf] = a;
    }
    __builtin_amdgcn_s_setprio(0);
#pragma unroll
    for (int r = 0; r < 4; ++r)
#pragma unroll
      for (int nf = 0; nf < 4; ++nf) p[r][nf] += aa[nf][r];

    // online softmax (exp2, defer-rescale)
#pragma unroll
    for (int r = 0; r < 4; ++r) {
      float mt = fmaxf(fmaxf(p[r][0], p[r][1]), fmaxf(p[r][2], p[r][3]));
      mt = rmax16(mt);
      if (mt > mrun[r] + DEFER_THR) {  // group-uniform condition
        float corr = fexp2(mrun[r] - mt);
        mrun[r] = mt;
        lsum[r] *= corr;
#pragma unroll
        for (int df = 0; df < 4; ++df) accO[df][r] *= corr;
      }
      float se = 0.f;
#pragma unroll
      for (int nf = 0; nf < 4; ++nf) {
        float e = fexp2(p[r][nf] - mrun[r]);
        p[r][nf] = e;
        se += e;
      }
      se = rsum16(se);
      lsum[r] += se;
#pragma unroll
      for (int nf = 0; nf < 4; ++nf)
        sP[w][g * 4 + r][nf * 16 + lc] = f2bf(p[r][nf]);
    }
    __builtin_amdgcn_s_setprio(1);
#pragma unroll
    for (int ks = 0; ks < 2; ++ks) {
      bf16x8 fp = *(const bf16x8*)&sP[w][lc][ks * 32 + g * 8];
#pragma unroll
      for (int df = 0; df < 4; ++df) {
        bf16x8 fv = *(const bf16x8*)&sVT[df * 16 + lc][ks * 32 + g * 8];
        accO[df] = mfma16(fp, fv, accO[df]);
      }
    }
    __builtin_amdgcn_s_setprio(0);
  }
#pragma unroll
  for (int r = 0; r < 4; ++r) {
    int i = i0 + w * 16 + g * 4 + r;
    size_t pb = ((size_t)(js * 32 + bn) * 1024 + i) * 64;
#pragma unroll
    for (int df = 0; df < 4; ++df) part[pb + df * 16 + lc] = f2bf(accO[df][r]);
    if (lc == 0) {
      size_t mb = (((size_t)js * 32 + bn) * 1024 + i) * 2;
      ml[mb] = mrun[r];
      ml[mb + 1] = lsum[r];
    }
  }
}

// ---------------- combine the two j-splits (exp2 basis, bf16 partials) ----------------
__global__ __launch_bounds__(256) void combine_kernel(const unsigned short* __restrict__ part,
                                                      const float* __restrict__ ml,
                                                      unsigned short* __restrict__ av) {
  int gw = blockIdx.x * 4 + (threadIdx.x >> 6);
  int lane = threadIdx.x & 63;
  int bn = gw >> 10, i = gw & 1023;
  int b = bn >> 4, n = bn & 15;
  float m0 = ml[((size_t)bn * 1024 + i) * 2];
  float l0 = ml[((size_t)bn * 1024 + i) * 2 + 1];
  float m1 = ml[(((size_t)32 + bn) * 1024 + i) * 2];
  float l1 = ml[(((size_t)32 + bn) * 1024 + i) * 2 + 1];
  float mx = fmaxf(m0, m1);
  float w0 = fexp2(m0 - mx), w1 = fexp2(m1 - mx);
  float inv = 1.f / (l0 * w0 + l1 * w1);
  float o = bf2f(part[((size_t)bn * 1024 + i) * 64 + lane]) * w0 +
            bf2f(part[(((size_t)32 + bn) * 1024 + i) * 64 + lane]) * w1;
  av[((size_t)i * 2 + b) * 1024 + n * 64 + lane] = f2bf(o * inv);
}

// ---------------- residual + LayerNorm ----------------
__global__ __launch_bounds__(256) void ln_kernel(const float* __restrict__ gout,
                                                 const float* __restrict__ h,
                                                 const float* __restrict__ gamma,
                                                 const float* __restrict__ beta,
                                                 float* __restrict__ out) {
  __shared__ float red[8];
  const int row = blockIdx.x;
  const int tid = threadIdx.x;
  float x[4];
  float s = 0.f;
#pragma unroll
  for (int q = 0; q < 4; ++q) {
    int d = tid + q * 256;
    x[q] = gout[(size_t)row * 1024 + d] + h[(size_t)row * 1024 + d];
    s += x[q];
  }
#pragma unroll
  for (int m = 1; m < 64; m <<= 1) s += __shfl_xor(s, m);
  if ((tid & 63) == 0) red[tid >> 6] = s;
  __syncthreads();
  s = red[0] + red[1] + red[2] + red[3];
  float mu = s * (1.f / 1024.f);
  float v = 0.f;
#pragma unroll
  for (int q = 0; q < 4; ++q) {
    float dd = x[q] - mu;
    v += dd * dd;
  }
#pragma unroll
  for (int m = 1; m < 64; m <<= 1) v += __shfl_xor(v, m);
  if ((tid & 63) == 0) red[4 + (tid >> 6)] = v;
  __syncthreads();
  v = red[4] + red[5] + red[6] + red[7];
  float rstd = rsqrtf(v * (1.f / 1024.f) + 1e-12f);
#pragma unroll
  for (int q = 0; q < 4; ++q) {
    int d = tid + q * 256;
    out[(size_t)row * 1024 + d] = (x[q] - mu) * rstd * gamma[d] + beta[d];
  }
}

extern "C" void kernel_launch(void* const* d_in, const int* in_sizes, int n_in,
                              void* d_out, int out_size, void* d_ws, size_t ws_size,
                              hipStream_t stream) {
  const float* h = (const float*)d_in[0];
  const float* r = (const float*)d_in[1];
  const unsigned char* seg = (const unsigned char*)d_in[2];
  const float* mask = (const float*)d_in[3];
  const float* wq = (const float*)d_in[4];
  const float* wk = (const float*)d_in[5];
  const float* wv = (const float*)d_in[6];
  const float* wr = (const float*)d_in[7];
  const float* wo = (const float*)d_in[8];
  const float* rwb = (const float*)d_in[9];
  const float* rrb = (const float*)d_in[10];
  const float* rsb = (const float*)d_in[11];
  const float* seg_embed = (const float*)d_in[12];
  const float* gamma = (const float*)d_in[13];
  const float* beta = (const float*)d_in[14];
  float* out = (float*)d_out;

  char* ws = (char*)d_ws;
  size_t off = 0;
  auto alloc = [&](size_t bytes) {
    size_t cur = off;
    off = (off + bytes + 255) & ~(size_t)255;
    return cur;
  };
  unsigned short* hb = (unsigned short*)(ws + alloc(2048 * 1024 * 2));
  unsigned short* rb = (unsigned short*)(ws + alloc(4096 * 1024 * 2));
  unsigned short* wq_t = (unsigned short*)(ws + alloc(1024 * 1024 * 2));
  unsigned short* wk_t = (unsigned short*)(ws + alloc(1024 * 1024 * 2));
  unsigned short* wv_t = (unsigned short*)(ws + alloc(1024 * 1024 * 2));
  unsigned short* wr_t = (unsigned short*)(ws + alloc(1024 * 1024 * 2));
  unsigned short* wo_b = (unsigned short*)(ws + alloc(1024 * 1024 * 2));
  unsigned short* qwb = (unsigned short*)(ws + alloc(2048 * 1024 * 2));
  unsigned short* qrb = (unsigned short*)(ws + alloc(2048 * 1024 * 2));
  unsigned short* khb = (unsigned short*)(ws + alloc(2048 * 1024 * 2));
  unsigned short* vhb = (unsigned short*)(ws + alloc(2048 * 1024 * 2));
  unsigned short* krhb = (unsigned short*)(ws + alloc(4096 * 1024 * 2));
  unsigned short* vTb = (unsigned short*)(ws + alloc(2048 * 1024 * 2));
  float* dvb = (float*)(ws + alloc(2048 * 16 * 4));
  unsigned int* segmask = (unsigned int*)(ws + alloc(2 * 1024 * 1024 * 4));
  unsigned short* avb = (unsigned short*)(ws + alloc(2048 * 1024 * 2));
  float* gout = (float*)(ws + alloc(2048 * 1024 * 4));
  unsigned short* part = (unsigned short*)(ws + alloc((size_t)2 * 32 * 1024 * 64 * 2));
  float* mlb = (float*)(ws + alloc((size_t)2 * 32 * 1024 * 2 * 4));
  (void)ws_size; (void)in_sizes; (void)n_in; (void)out_size;

  pre_kernel<<<15360, 256, 0, stream>>>(h, r, wo, wq, wk, wv, wr, seg, mask,
                                        hb, rb, wo_b, wq_t, wk_t, wv_t, wr_t, segmask);

  proj4_kernel<<<640, 512, 0, stream>>>(hb, rb, wq_t, wk_t, wv_t, wr_t, rwb, rrb, rsb,
                                        seg_embed, qwb, qrb, khb, vhb, krhb, dvb);

  transpose_v<<<dim3(16, 32), 256, 0, stream>>>(vhb, vTb);

  attn_kernel<<<dim3(32, 8, 2), 512, 0, stream>>>(qwb, qrb, khb, krhb, vTb,
                                                  dvb, segmask, part, mlb);
  combine_kernel<<<8192, 256, 0, stream>>>(part, mlb, avb);

  gemm64_out<<<dim3(8, 32), 512, 0, stream>>>(avb, wo_b, gout);
  ln_kernel<<<2048, 256, 0, stream>>>(gout, h, gamma, beta, out);
}

// Round 14
// 126.235 us; speedup vs baseline: 1.3636x; 1.3636x over previous
//
#include <hip/hip_runtime.h>

typedef __bf16 bf16x8 __attribute__((ext_vector_type(8)));
typedef float f32x4 __attribute__((ext_vector_type(4)));
typedef unsigned short us4 __attribute__((ext_vector_type(4)));

__device__ __forceinline__ unsigned short f2bf(float f) {
  unsigned int u = __builtin_bit_cast(unsigned int, f);
  u += 0x7fffu + ((u >> 16) & 1u);
  return (unsigned short)(u >> 16);
}
__device__ __forceinline__ float bf2f(unsigned short s) {
  unsigned int u = ((unsigned int)s) << 16;
  return __builtin_bit_cast(float, u);
}
__device__ __forceinline__ f32x4 mfma16(bf16x8 a, bf16x8 b, f32x4 c) {
  return __builtin_amdgcn_mfma_f32_16x16x32_bf16(a, b, c, 0, 0, 0);
}
__device__ __forceinline__ void gload16(const void* g, void* l) {
  __builtin_amdgcn_global_load_lds(
      (const __attribute__((address_space(1))) unsigned int*)g,
      (__attribute__((address_space(3))) unsigned int*)l, 16, 0, 0);
}
__device__ __forceinline__ float fexp2(float x) {
  float r;
  asm("v_exp_f32 %0, %1" : "=v"(r) : "v"(x));
  return r;
}
template <int CTRL>
__device__ __forceinline__ float dppf(float x) {
  return __builtin_bit_cast(
      float, __builtin_amdgcn_mov_dpp(__builtin_bit_cast(int, x), CTRL, 0xf, 0xf, true));
}
__device__ __forceinline__ float rmax16(float x) {
  x = fmaxf(x, dppf<0xB1>(x));
  x = fmaxf(x, dppf<0x4E>(x));
  x = fmaxf(x, dppf<0x124>(x));
  x = fmaxf(x, dppf<0x128>(x));
  return x;
}
__device__ __forceinline__ float rsum16(float x) {
  x += dppf<0xB1>(x);
  x += dppf<0x4E>(x);
  x += dppf<0x124>(x);
  x += dppf<0x128>(x);
  return x;
}

#define QSCL 0.18033688011112042f  /* 0.125 * log2(e) */
#define LOG2E 1.4426950408889634f

// ---------------- fused preprocessing: casts + weight transposes + segmask, one launch ----------------
__global__ __launch_bounds__(256) void pre_kernel(
    const float* __restrict__ h, const float* __restrict__ r, const float* __restrict__ wo,
    const float* __restrict__ w0, const float* __restrict__ w1,
    const float* __restrict__ w2, const float* __restrict__ w3,
    const unsigned char* __restrict__ seg, const float* __restrict__ mask,
    unsigned short* __restrict__ hb, unsigned short* __restrict__ rb,
    unsigned short* __restrict__ wo_b,
    unsigned short* __restrict__ o0, unsigned short* __restrict__ o1,
    unsigned short* __restrict__ o2, unsigned short* __restrict__ o3,
    unsigned int* __restrict__ segout) {
  __shared__ float t[32][33];
  const int bx = blockIdx.x;
  const int tid = threadIdx.x;
  if (bx < 7168) {
    int idx = bx * 256 + tid;
    const float* in;
    unsigned short* out;
    int o;
    if (idx < 524288) { in = h; out = hb; o = idx; }
    else if (idx < 1572864) { in = r; out = rb; o = idx - 524288; }
    else { in = wo; out = wo_b; o = idx - 1572864; }
    float4 v = ((const float4*)in)[o];
    us4 tt;
    tt[0] = f2bf(v.x); tt[1] = f2bf(v.y); tt[2] = f2bf(v.z); tt[3] = f2bf(v.w);
    *(us4*)&out[o * 4] = tt;
  } else if (bx < 11264) {
    int zz = bx - 7168;
    int z = zz >> 10, tt_ = zz & 1023;
    const float* in = z == 0 ? w0 : (z == 1 ? w1 : (z == 2 ? w2 : w3));
    unsigned short* out = z == 0 ? o0 : (z == 1 ? o1 : (z == 2 ? o2 : o3));
    int k0 = (tt_ >> 5) * 32;
    int n0 = (tt_ & 31) * 32;
    int rr = tid >> 5;
    int c = tid & 31;
#pragma unroll
    for (int s = 0; s < 4; ++s)
      t[rr + s * 8][c] = in[(k0 + rr + s * 8) * 1024 + n0 + c];
    __syncthreads();
#pragma unroll
    for (int s = 0; s < 4; ++s)
      out[(n0 + rr + s * 8) * 1024 + k0 + c] = f2bf(t[c][rr + s * 8]);
  } else {
    int ij = (bx - 11264) * 256 + tid;
    unsigned short sv = *(const unsigned short*)&seg[ij * 2];
    float2 mv = *(const float2*)&mask[(size_t)ij * 2];
    unsigned int q0 = ((unsigned int)f2bf(mv.x * -1.4426950408889634e30f) << 16) |
                      ((sv & 0xffu) ? 0x3f80u : 0u);
    unsigned int q1 = ((unsigned int)f2bf(mv.y * -1.4426950408889634e30f) << 16) |
                      ((sv >> 8) ? 0x3f80u : 0u);
    segout[ij] = q0;
    segout[1048576 + ij] = q1;
  }
}

// ---------------- all 4 projections (R7 structure) + fused dv epilogue ----------------
__global__ __launch_bounds__(512) void proj4_kernel(
    const unsigned short* __restrict__ hb, const unsigned short* __restrict__ rb,
    const unsigned short* __restrict__ wq_t, const unsigned short* __restrict__ wk_t,
    const unsigned short* __restrict__ wv_t, const unsigned short* __restrict__ wr_t,
    const float* __restrict__ rwb, const float* __restrict__ rrb, const float* __restrict__ rsb,
    const float* __restrict__ seg_embed,
    unsigned short* __restrict__ qwb, unsigned short* __restrict__ qrb,
    unsigned short* __restrict__ khb, unsigned short* __restrict__ vhb,
    unsigned short* __restrict__ krhb,
    float* __restrict__ dvb) {
  __shared__ unsigned short sA[2][128 * 64];
  __shared__ unsigned short sB[2][128 * 64];
  const int bx = blockIdx.x;
  int sel, rblk;
  const unsigned short* A;
  if (bx < 384) { sel = bx >> 7; rblk = bx & 127; A = hb; }
  else { sel = 3; rblk = bx - 384; A = rb; }
  const unsigned short* Bt = sel == 0 ? wq_t : (sel == 1 ? wk_t : (sel == 2 ? wv_t : wr_t));
  const int n0 = (rblk & 7) * 128, m0 = (rblk >> 3) * 128;
  const int tid = threadIdx.x, lane = tid & 63, w = tid >> 6;
  const int wm = w >> 1, wn = w & 1, g = lane >> 4, lc = lane & 15;

  f32x4 acc[2][4] = {};

  auto STAGE = [&](int buf, int kt) {
#pragma unroll
    for (int s = 0; s < 2; ++s) {
      int c = s * 512 + tid;
      int row = c >> 3;
      int ko = ((c & 7) ^ (row & 7)) * 8;
      int lbase = (s * 512 + w * 64) * 8;
      gload16(&A[(size_t)(m0 + row) * 1024 + kt + ko], &sA[buf][lbase]);
      gload16(&Bt[(size_t)(n0 + row) * 1024 + kt + ko], &sB[buf][lbase]);
    }
  };

  STAGE(0, 0);
  __syncthreads();

  for (int kt = 0; kt < 1024; kt += 64) {
    const int cur = (kt >> 6) & 1;
    if (kt < 960) STAGE(cur ^ 1, kt + 64);
    bf16x8 af[2][2], bfr[4][2];
#pragma unroll
    for (int ks = 0; ks < 2; ++ks) {
#pragma unroll
      for (int mi = 0; mi < 2; ++mi) {
        int ra = wm * 32 + mi * 16 + lc;
        af[mi][ks] = *(const bf16x8*)&sA[cur][ra * 64 + (((ks * 4 + g) ^ (ra & 7)) * 8)];
      }
#pragma unroll
      for (int ni = 0; ni < 4; ++ni) {
        int rb_ = wn * 64 + ni * 16 + lc;
        bfr[ni][ks] = *(const bf16x8*)&sB[cur][rb_ * 64 + (((ks * 4 + g) ^ (rb_ & 7)) * 8)];
      }
    }
#pragma unroll
    for (int ks = 0; ks < 2; ++ks)
#pragma unroll
      for (int mi = 0; mi < 2; ++mi)
#pragma unroll
        for (int ni = 0; ni < 4; ++ni)
          acc[mi][ni] = mfma16(af[mi][ks], bfr[ni][ks], acc[mi][ni]);
    __syncthreads();
  }

  if (sel == 0) {
    const int hn = (n0 >> 6) + wn;
    float sedv[4], bwv[4], brv[4], bsv[4];
#pragma unroll
    for (int ni = 0; ni < 4; ++ni) {
      int col = n0 + wn * 64 + ni * 16 + lc;
      sedv[ni] = seg_embed[1024 + hn * 64 + ni * 16 + lc] - seg_embed[hn * 64 + ni * 16 + lc];
      bwv[ni] = rwb[col];
      brv[ni] = rrb[col];
      bsv[ni] = rsb[col];
    }
#pragma unroll
    for (int mi = 0; mi < 2; ++mi) {
      int rowb = m0 + wm * 32 + mi * 16 + g * 4;
#pragma unroll
      for (int r = 0; r < 4; ++r) {
        float e = 0.f;
#pragma unroll
        for (int ni = 0; ni < 4; ++ni) {
          int col = n0 + wn * 64 + ni * 16 + lc;
          float v = acc[mi][ni][r];
          size_t idx = (size_t)(rowb + r) * 1024 + col;
          qwb[idx] = f2bf((v + bwv[ni]) * QSCL);
          qrb[idx] = f2bf((v + brv[ni]) * QSCL);
          e += (v + bsv[ni]) * 0.125f * sedv[ni];
        }
        e = rsum16(e);
        if (lc == 0) {
          int ib = rowb + r;
          int i = ib >> 1, b = ib & 1;
          dvb[(b * 16 + hn) * 1024 + i] = e * LOG2E;
        }
      }
    }
  } else {
#pragma unroll
    for (int ni = 0; ni < 4; ++ni) {
      int col = n0 + wn * 64 + ni * 16 + lc;
#pragma unroll
      for (int mi = 0; mi < 2; ++mi) {
        int rowb = m0 + wm * 32 + mi * 16 + g * 4;
#pragma unroll
        for (int r = 0; r < 4; ++r) {
          float v = acc[mi][ni][r];
          size_t idx = (size_t)(rowb + r) * 1024 + col;
          if (sel == 1) khb[idx] = f2bf(v);
          else if (sel == 2) vhb[idx] = f2bf(v);
          else krhb[idx] = f2bf(v);
        }
      }
    }
  }
}

// ---------------- out-projection: 64x128 tile, 8 waves, BK=64, 2-phase dbuf, swizzled ----------------
__global__ __launch_bounds__(512) void gemm64_out(const unsigned short* __restrict__ A,
                                                  const unsigned short* __restrict__ Bt,
                                                  float* __restrict__ C) {
  __shared__ unsigned short sA[2][64 * 64];
  __shared__ unsigned short sB[2][128 * 64];
  const int tid = threadIdx.x, lane = tid & 63, w = tid >> 6;
  const int wm = w >> 2, wn = w & 3, g = lane >> 4, lc = lane & 15;
  const int m0 = blockIdx.y * 64, n0 = blockIdx.x * 128;
  f32x4 acc[2][2] = {};

  auto STAGE = [&](int buf, int kt) {
    {
      int c = tid;
      int row = c >> 3;
      int ko = ((c & 7) ^ (row & 7)) * 8;
      gload16(&A[(size_t)(m0 + row) * 1024 + kt + ko], &sA[buf][w * 64 * 8]);
    }
#pragma unroll
    for (int s = 0; s < 2; ++s) {
      int c = s * 512 + tid;
      int row = c >> 3;
      int ko = ((c & 7) ^ (row & 7)) * 8;
      gload16(&Bt[(size_t)(n0 + row) * 1024 + kt + ko], &sB[buf][(s * 512 + w * 64) * 8]);
    }
  };

  STAGE(0, 0);
  __syncthreads();

  for (int kt = 0; kt < 1024; kt += 64) {
    const int cur = (kt >> 6) & 1;
    if (kt < 960) STAGE(cur ^ 1, kt + 64);
    bf16x8 af[2][2], bfr[2][2];
#pragma unroll
    for (int ks = 0; ks < 2; ++ks) {
#pragma unroll
      for (int mi = 0; mi < 2; ++mi) {
        int ra = wm * 32 + mi * 16 + lc;
        af[mi][ks] = *(const bf16x8*)&sA[cur][ra * 64 + (((ks * 4 + g) ^ (ra & 7)) * 8)];
      }
#pragma unroll
      for (int ni = 0; ni < 2; ++ni) {
        int rb_ = wn * 32 + ni * 16 + lc;
        bfr[ni][ks] = *(const bf16x8*)&sB[cur][rb_ * 64 + (((ks * 4 + g) ^ (rb_ & 7)) * 8)];
      }
    }
#pragma unroll
    for (int ks = 0; ks < 2; ++ks)
#pragma unroll
      for (int mi = 0; mi < 2; ++mi)
#pragma unroll
        for (int ni = 0; ni < 2; ++ni)
          acc[mi][ni] = mfma16(af[mi][ks], bfr[ni][ks], acc[mi][ni]);
    __syncthreads();
  }
#pragma unroll
  for (int ni = 0; ni < 2; ++ni) {
    int col = n0 + wn * 32 + ni * 16 + lc;
#pragma unroll
    for (int mi = 0; mi < 2; ++mi) {
      int rowb = m0 + wm * 32 + mi * 16 + g * 4;
#pragma unroll
      for (int r = 0; r < 4; ++r)
        C[(size_t)(rowb + r) * 1024 + col] = acc[mi][ni][r];
    }
  }
}

// ---------------- V transpose ----------------
__global__ __launch_bounds__(256) void transpose_v(const unsigned short* __restrict__ vh,
                                                   unsigned short* __restrict__ vT) {
  __shared__ unsigned short t[64][65];
  const int bn = blockIdx.y, j0 = blockIdx.x * 64;
  const int b = bn >> 4, n = bn & 15;
  const int r = threadIdx.x >> 4;
  const int c4 = (threadIdx.x & 15) * 4;
#pragma unroll
  for (int s = 0; s < 4; ++s) {
    int j = r + s * 16;
    us4 v = *(const us4*)&vh[((size_t)(j0 + j) * 2 + b) * 1024 + n * 64 + c4];
    t[j][c4 + 0] = v[0]; t[j][c4 + 1] = v[1]; t[j][c4 + 2] = v[2]; t[j][c4 + 3] = v[3];
  }
  __syncthreads();
#pragma unroll
  for (int s = 0; s < 4; ++s) {
    int d = r + s * 16;
    us4 v;
    v[0] = t[c4 + 0][d]; v[1] = t[c4 + 1][d]; v[2] = t[c4 + 2][d]; v[3] = t[c4 + 3][d];
    *(us4*)&vT[((size_t)bn * 64 + d) * 1024 + j0 + c4] = v;
  }
}

// ---------------- fused relative attention: EXACT R12 structure; bf16 part epilogue only ----------------
__global__ __launch_bounds__(512, 4) void attn_kernel(
    const unsigned short* __restrict__ qw, const unsigned short* __restrict__ qr,
    const unsigned short* __restrict__ kh, const unsigned short* __restrict__ krh,
    const unsigned short* __restrict__ vT,
    const float* __restrict__ dvb,
    const unsigned int* __restrict__ segmask,
    unsigned short* __restrict__ part, float* __restrict__ ml) {
  __shared__ unsigned short sK[64][72];
  __shared__ unsigned short sVT[64][72];
  __shared__ unsigned short sKR[256][72];  // circular band, slot = jr & 255
  __shared__ unsigned short sP[8][16][80];

  const int tid = threadIdx.x, lane = tid & 63, w = tid >> 6;
  const int g = lane >> 4, lc = lane & 15;
  const int bn = blockIdx.x, b = bn >> 4, n = bn & 15;
  const int i0 = blockIdx.y * 128;
  const int js = blockIdx.z;
  const int S0 = 1024 + js * 512 - i0 - 127;

  bf16x8 fqw[2], fqr[2];
  const int qrow = i0 + w * 16 + lc;
#pragma unroll
  for (int ks = 0; ks < 2; ++ks) {
    size_t off = ((size_t)qrow * 2 + b) * 1024 + n * 64 + ks * 32 + g * 8;
    fqw[ks] = *(const bf16x8*)&qw[off];
    fqr[ks] = *(const bf16x8*)&qr[off];
  }
  float dv[4];
  unsigned int smoff[4];
#pragma unroll
  for (int r = 0; r < 4; ++r) {
    int i = i0 + w * 16 + g * 4 + r;
    dv[r] = dvb[bn * 1024 + i];
    smoff[r] = ((unsigned)b << 20) | ((unsigned)i << 10) | (unsigned)lc;
  }
  float mrun[4], lsum[4];
  f32x4 accO[4] = {};
#pragma unroll
  for (int r = 0; r < 4; ++r) { mrun[r] = -3e38f; lsum[r] = 0.f; }

  const int srow = tid >> 3;
  const int sko = (tid & 7) * 8;

#pragma unroll
  for (int pp = 0; pp < 3; ++pp) {
    int jr = S0 + pp * 64 + srow;
    *(uint4*)&sKR[jr & 255][sko] =
        *(const uint4*)&krh[((size_t)jr * 2 + b) * 1024 + n * 64 + sko];
  }
  int j0 = js * 512;
  uint4 rK = *(const uint4*)&kh[((size_t)(j0 + srow) * 2 + b) * 1024 + n * 64 + sko];
  uint4 rV = *(const uint4*)&vT[((size_t)bn * 64 + srow) * 1024 + j0 + sko];
  uint4 rR = *(const uint4*)&krh[((size_t)(S0 + 192 + srow) * 2 + b) * 1024 + n * 64 + sko];

  for (int t = 0; t < 8; ++t) {
    j0 = (js * 8 + t) * 64;
    __syncthreads();
    *(uint4*)&sK[srow][sko] = rK;
    *(uint4*)&sVT[srow][sko] = rV;
    if (t < 7) {
      *(uint4*)&sKR[(S0 + 192 + t * 64 + srow) & 255][sko] = rR;
      int j0n = j0 + 64;
      rK = *(const uint4*)&kh[((size_t)(j0n + srow) * 2 + b) * 1024 + n * 64 + sko];
      rV = *(const uint4*)&vT[((size_t)bn * 64 + srow) * 1024 + j0n + sko];
      if (t < 6) {
        int jr = S0 + 256 + t * 64 + srow;
        if (jr > 2047) jr = 2047;
        rR = *(const uint4*)&krh[((size_t)jr * 2 + b) * 1024 + n * 64 + sko];
      }
    }
    unsigned int msv[4][4];
#pragma unroll
    for (int r = 0; r < 4; ++r)
#pragma unroll
      for (int nf = 0; nf < 4; ++nf)
        msv[r][nf] = segmask[smoff[r] + j0 + nf * 16];
    __syncthreads();

    const int base = S0 + t * 64 + (7 - w) * 16;
    f32x4 bdk[5];
#pragma unroll
    for (int k = 0; k < 5; ++k) {
      f32x4 a = {0.f, 0.f, 0.f, 0.f};
#pragma unroll
      for (int ks = 0; ks < 2; ++ks) {
        bf16x8 fk = *(const bf16x8*)&sKR[(base + k * 16 + lc) & 255][ks * 32 + g * 8];
        a = mfma16(fqr[ks], fk, a);
      }
      bdk[k] = a;
    }
    float p[4][4];
#pragma unroll
    for (int r = 0; r < 4; ++r) {
      const int a_ = g * 4 + r;
      const int srcl = (lane & 48) | ((lc + 15 - a_) & 15);
      float s0 = __shfl(bdk[0][r], srcl);
      float s1 = __shfl(bdk[1][r], srcl);
      float s2 = __shfl(bdk[2][r], srcl);
      float s3 = __shfl(bdk[3][r], srcl);
      float s4 = __shfl(bdk[4][r], srcl);
      const bool lo = lc <= a_;
#pragma unroll
      for (int nf = 0; nf < 4; ++nf) {
        unsigned int u = msv[r][nf];
        float sgd = (u & 0xffffu) ? dv[r] : 0.f;
        float mkv = bf2f((unsigned short)(u >> 16));
        float bdv = lo ? (nf == 0 ? s0 : nf == 1 ? s1 : nf == 2 ? s2 : s3)
                       : (nf == 0 ? s1 : nf == 1 ? s2 : nf == 2 ? s3 : s4);
        p[r][nf] = sgd + mkv + bdv;
      }
    }
    f32x4 aa[4];
#pragma unroll
    for (int nf = 0; nf < 4; ++nf) {
      f32x4 a = {0.f, 0.f, 0.f, 0.f};
#pragma unroll
      for (int ks = 0; ks < 2; ++ks) {
        bf16x8 fk = *(const bf16x8*)&sK[nf * 16 + lc][ks * 32 + g * 8];
        a = mfma16(fqw[ks], fk, a);
      }
      aa[nf] = a;
    }
#pragma unroll
    for (int r = 0; r < 4; ++r)
#pragma unroll
      for (int nf = 0; nf < 4; ++nf) p[r][nf] += aa[nf][r];

#pragma unroll
    for (int r = 0; r < 4; ++r) {
      float mt = fmaxf(fmaxf(p[r][0], p[r][1]), fmaxf(p[r][2], p[r][3]));
      mt = rmax16(mt);
      float mnew = fmaxf(mrun[r], mt);
      float corr = fexp2(mrun[r] - mnew);
      mrun[r] = mnew;
      float se = 0.f;
#pragma unroll
      for (int nf = 0; nf < 4; ++nf) {
        float e = fexp2(p[r][nf] - mnew);
        p[r][nf] = e;
        se += e;
      }
      se = rsum16(se);
      lsum[r] = lsum[r] * corr + se;
#pragma unroll
      for (int df = 0; df < 4; ++df) accO[df][r] *= corr;
#pragma unroll
      for (int nf = 0; nf < 4; ++nf)
        sP[w][g * 4 + r][nf * 16 + lc] = f2bf(p[r][nf]);
    }
#pragma unroll
    for (int ks = 0; ks < 2; ++ks) {
      bf16x8 fp = *(const bf16x8*)&sP[w][lc][ks * 32 + g * 8];
#pragma unroll
      for (int df = 0; df < 4; ++df) {
        bf16x8 fv = *(const bf16x8*)&sVT[df * 16 + lc][ks * 32 + g * 8];
        accO[df] = mfma16(fp, fv, accO[df]);
      }
    }
  }
#pragma unroll
  for (int r = 0; r < 4; ++r) {
    int i = i0 + w * 16 + g * 4 + r;
    size_t pb = ((size_t)(js * 32 + bn) * 1024 + i) * 64;
#pragma unroll
    for (int df = 0; df < 4; ++df) part[pb + df * 16 + lc] = f2bf(accO[df][r]);
    if (lc == 0) {
      size_t mb = (((size_t)js * 32 + bn) * 1024 + i) * 2;
      ml[mb] = mrun[r];
      ml[mb + 1] = lsum[r];
    }
  }
}

// ---------------- combine the two j-splits (exp2 basis, bf16 partials) ----------------
__global__ __launch_bounds__(256) void combine_kernel(const unsigned short* __restrict__ part,
                                                      const float* __restrict__ ml,
                                                      unsigned short* __restrict__ av) {
  int gw = blockIdx.x * 4 + (threadIdx.x >> 6);
  int lane = threadIdx.x & 63;
  int bn = gw >> 10, i = gw & 1023;
  int b = bn >> 4, n = bn & 15;
  float m0 = ml[((size_t)bn * 1024 + i) * 2];
  float l0 = ml[((size_t)bn * 1024 + i) * 2 + 1];
  float m1 = ml[(((size_t)32 + bn) * 1024 + i) * 2];
  float l1 = ml[(((size_t)32 + bn) * 1024 + i) * 2 + 1];
  float mx = fmaxf(m0, m1);
  float w0 = fexp2(m0 - mx), w1 = fexp2(m1 - mx);
  float inv = 1.f / (l0 * w0 + l1 * w1);
  float o = bf2f(part[((size_t)bn * 1024 + i) * 64 + lane]) * w0 +
            bf2f(part[(((size_t)32 + bn) * 1024 + i) * 64 + lane]) * w1;
  av[((size_t)i * 2 + b) * 1024 + n * 64 + lane] = f2bf(o * inv);
}

// ---------------- residual + LayerNorm ----------------
__global__ __launch_bounds__(256) void ln_kernel(const float* __restrict__ gout,
                                                 const float* __restrict__ h,
                                                 const float* __restrict__ gamma,
                                                 const float* __restrict__ beta,
                                                 float* __restrict__ out) {
  __shared__ float red[8];
  const int row = blockIdx.x;
  const int tid = threadIdx.x;
  float x[4];
  float s = 0.f;
#pragma unroll
  for (int q = 0; q < 4; ++q) {
    int d = tid + q * 256;
    x[q] = gout[(size_t)row * 1024 + d] + h[(size_t)row * 1024 + d];
    s += x[q];
  }
#pragma unroll
  for (int m = 1; m < 64; m <<= 1) s += __shfl_xor(s, m);
  if ((tid & 63) == 0) red[tid >> 6] = s;
  __syncthreads();
  s = red[0] + red[1] + red[2] + red[3];
  float mu = s * (1.f / 1024.f);
  float v = 0.f;
#pragma unroll
  for (int q = 0; q < 4; ++q) {
    float dd = x[q] - mu;
    v += dd * dd;
  }
#pragma unroll
  for (int m = 1; m < 64; m <<= 1) v += __shfl_xor(v, m);
  if ((tid & 63) == 0) red[4 + (tid >> 6)] = v;
  __syncthreads();
  v = red[4] + red[5] + red[6] + red[7];
  float rstd = rsqrtf(v * (1.f / 1024.f) + 1e-12f);
#pragma unroll
  for (int q = 0; q < 4; ++q) {
    int d = tid + q * 256;
    out[(size_t)row * 1024 + d] = (x[q] - mu) * rstd * gamma[d] + beta[d];
  }
}

extern "C" void kernel_launch(void* const* d_in, const int* in_sizes, int n_in,
                              void* d_out, int out_size, void* d_ws, size_t ws_size,
                              hipStream_t stream) {
  const float* h = (const float*)d_in[0];
  const float* r = (const float*)d_in[1];
  const unsigned char* seg = (const unsigned char*)d_in[2];
  const float* mask = (const float*)d_in[3];
  const float* wq = (const float*)d_in[4];
  const float* wk = (const float*)d_in[5];
  const float* wv = (const float*)d_in[6];
  const float* wr = (const float*)d_in[7];
  const float* wo = (const float*)d_in[8];
  const float* rwb = (const float*)d_in[9];
  const float* rrb = (const float*)d_in[10];
  const float* rsb = (const float*)d_in[11];
  const float* seg_embed = (const float*)d_in[12];
  const float* gamma = (const float*)d_in[13];
  const float* beta = (const float*)d_in[14];
  float* out = (float*)d_out;

  char* ws = (char*)d_ws;
  size_t off = 0;
  auto alloc = [&](size_t bytes) {
    size_t cur = off;
    off = (off + bytes + 255) & ~(size_t)255;
    return cur;
  };
  unsigned short* hb = (unsigned short*)(ws + alloc(2048 * 1024 * 2));
  unsigned short* rb = (unsigned short*)(ws + alloc(4096 * 1024 * 2));
  unsigned short* wq_t = (unsigned short*)(ws + alloc(1024 * 1024 * 2));
  unsigned short* wk_t = (unsigned short*)(ws + alloc(1024 * 1024 * 2));
  unsigned short* wv_t = (unsigned short*)(ws + alloc(1024 * 1024 * 2));
  unsigned short* wr_t = (unsigned short*)(ws + alloc(1024 * 1024 * 2));
  unsigned short* wo_b = (unsigned short*)(ws + alloc(1024 * 1024 * 2));
  unsigned short* qwb = (unsigned short*)(ws + alloc(2048 * 1024 * 2));
  unsigned short* qrb = (unsigned short*)(ws + alloc(2048 * 1024 * 2));
  unsigned short* khb = (unsigned short*)(ws + alloc(2048 * 1024 * 2));
  unsigned short* vhb = (unsigned short*)(ws + alloc(2048 * 1024 * 2));
  unsigned short* krhb = (unsigned short*)(ws + alloc(4096 * 1024 * 2));
  unsigned short* vTb = (unsigned short*)(ws + alloc(2048 * 1024 * 2));
  float* dvb = (float*)(ws + alloc(2048 * 16 * 4));
  unsigned int* segmask = (unsigned int*)(ws + alloc(2 * 1024 * 1024 * 4));
  unsigned short* avb = (unsigned short*)(ws + alloc(2048 * 1024 * 2));
  float* gout = (float*)(ws + alloc(2048 * 1024 * 4));
  unsigned short* part = (unsigned short*)(ws + alloc((size_t)2 * 32 * 1024 * 64 * 2));
  float* mlb = (float*)(ws + alloc((size_t)2 * 32 * 1024 * 2 * 4));
  (void)ws_size; (void)in_sizes; (void)n_in; (void)out_size;

  pre_kernel<<<15360, 256, 0, stream>>>(h, r, wo, wq, wk, wv, wr, seg, mask,
                                        hb, rb, wo_b, wq_t, wk_t, wv_t, wr_t, segmask);

  proj4_kernel<<<640, 512, 0, stream>>>(hb, rb, wq_t, wk_t, wv_t, wr_t, rwb, rrb, rsb,
                                        seg_embed, qwb, qrb, khb, vhb, krhb, dvb);

  transpose_v<<<dim3(16, 32), 256, 0, stream>>>(vhb, vTb);

  attn_kernel<<<dim3(32, 8, 2), 512, 0, stream>>>(qwb, qrb, khb, krhb, vTb,
                                                  dvb, segmask, part, mlb);
  combine_kernel<<<8192, 256, 0, stream>>>(part, mlb, avb);

  gemm64_out<<<dim3(8, 32), 512, 0, stream>>>(avb, wo_b, gout);
  ln_kernel<<<2048, 256, 0, stream>>>(gout, h, gamma, beta, out);
}

// Round 15
// 125.747 us; speedup vs baseline: 1.3689x; 1.0039x over previous
//
#include <hip/hip_runtime.h>

typedef __bf16 bf16x8 __attribute__((ext_vector_type(8)));
typedef float f32x4 __attribute__((ext_vector_type(4)));
typedef unsigned short us4 __attribute__((ext_vector_type(4)));

__device__ __forceinline__ unsigned short f2bf(float f) {
  unsigned int u = __builtin_bit_cast(unsigned int, f);
  u += 0x7fffu + ((u >> 16) & 1u);
  return (unsigned short)(u >> 16);
}
__device__ __forceinline__ float bf2f(unsigned short s) {
  unsigned int u = ((unsigned int)s) << 16;
  return __builtin_bit_cast(float, u);
}
__device__ __forceinline__ f32x4 mfma16(bf16x8 a, bf16x8 b, f32x4 c) {
  return __builtin_amdgcn_mfma_f32_16x16x32_bf16(a, b, c, 0, 0, 0);
}
__device__ __forceinline__ void gload16(const void* g, void* l) {
  __builtin_amdgcn_global_load_lds(
      (const __attribute__((address_space(1))) unsigned int*)g,
      (__attribute__((address_space(3))) unsigned int*)l, 16, 0, 0);
}
__device__ __forceinline__ float fexp2(float x) {
  float r;
  asm("v_exp_f32 %0, %1" : "=v"(r) : "v"(x));
  return r;
}
template <int CTRL>
__device__ __forceinline__ float dppf(float x) {
  return __builtin_bit_cast(
      float, __builtin_amdgcn_mov_dpp(__builtin_bit_cast(int, x), CTRL, 0xf, 0xf, true));
}
__device__ __forceinline__ float rmax16(float x) {
  x = fmaxf(x, dppf<0xB1>(x));
  x = fmaxf(x, dppf<0x4E>(x));
  x = fmaxf(x, dppf<0x124>(x));
  x = fmaxf(x, dppf<0x128>(x));
  return x;
}
__device__ __forceinline__ float rsum16(float x) {
  x += dppf<0xB1>(x);
  x += dppf<0x4E>(x);
  x += dppf<0x124>(x);
  x += dppf<0x128>(x);
  return x;
}

#define QSCL 0.18033688011112042f  /* 0.125 * log2(e) */
#define LOG2E 1.4426950408889634f

// ---------------- fused preprocessing: casts + weight transposes + segmask, one launch ----------------
__global__ __launch_bounds__(256) void pre_kernel(
    const float* __restrict__ h, const float* __restrict__ r, const float* __restrict__ wo,
    const float* __restrict__ w0, const float* __restrict__ w1,
    const float* __restrict__ w2, const float* __restrict__ w3,
    const unsigned char* __restrict__ seg, const float* __restrict__ mask,
    unsigned short* __restrict__ hb, unsigned short* __restrict__ rb,
    unsigned short* __restrict__ wo_b,
    unsigned short* __restrict__ o0, unsigned short* __restrict__ o1,
    unsigned short* __restrict__ o2, unsigned short* __restrict__ o3,
    unsigned int* __restrict__ segout) {
  __shared__ float t[32][33];
  const int bx = blockIdx.x;
  const int tid = threadIdx.x;
  if (bx < 7168) {
    int idx = bx * 256 + tid;
    const float* in;
    unsigned short* out;
    int o;
    if (idx < 524288) { in = h; out = hb; o = idx; }
    else if (idx < 1572864) { in = r; out = rb; o = idx - 524288; }
    else { in = wo; out = wo_b; o = idx - 1572864; }
    float4 v = ((const float4*)in)[o];
    us4 tt;
    tt[0] = f2bf(v.x); tt[1] = f2bf(v.y); tt[2] = f2bf(v.z); tt[3] = f2bf(v.w);
    *(us4*)&out[o * 4] = tt;
  } else if (bx < 11264) {
    int zz = bx - 7168;
    int z = zz >> 10, tt_ = zz & 1023;
    const float* in = z == 0 ? w0 : (z == 1 ? w1 : (z == 2 ? w2 : w3));
    unsigned short* out = z == 0 ? o0 : (z == 1 ? o1 : (z == 2 ? o2 : o3));
    int k0 = (tt_ >> 5) * 32;
    int n0 = (tt_ & 31) * 32;
    int rr = tid >> 5;
    int c = tid & 31;
#pragma unroll
    for (int s = 0; s < 4; ++s)
      t[rr + s * 8][c] = in[(k0 + rr + s * 8) * 1024 + n0 + c];
    __syncthreads();
#pragma unroll
    for (int s = 0; s < 4; ++s)
      out[(n0 + rr + s * 8) * 1024 + k0 + c] = f2bf(t[c][rr + s * 8]);
  } else {
    int ij = (bx - 11264) * 256 + tid;
    unsigned short sv = *(const unsigned short*)&seg[ij * 2];
    float2 mv = *(const float2*)&mask[(size_t)ij * 2];
    unsigned int q0 = ((unsigned int)f2bf(mv.x * -1.4426950408889634e30f) << 16) |
                      ((sv & 0xffu) ? 0x3f80u : 0u);
    unsigned int q1 = ((unsigned int)f2bf(mv.y * -1.4426950408889634e30f) << 16) |
                      ((sv >> 8) ? 0x3f80u : 0u);
    segout[ij] = q0;
    segout[1048576 + ij] = q1;
  }
}

// ---------------- all 4 projections (R7 structure) + fused dv epilogue ----------------
__global__ __launch_bounds__(512) void proj4_kernel(
    const unsigned short* __restrict__ hb, const unsigned short* __restrict__ rb,
    const unsigned short* __restrict__ wq_t, const unsigned short* __restrict__ wk_t,
    const unsigned short* __restrict__ wv_t, const unsigned short* __restrict__ wr_t,
    const float* __restrict__ rwb, const float* __restrict__ rrb, const float* __restrict__ rsb,
    const float* __restrict__ seg_embed,
    unsigned short* __restrict__ qwb, unsigned short* __restrict__ qrb,
    unsigned short* __restrict__ khb, unsigned short* __restrict__ vhb,
    unsigned short* __restrict__ krhb,
    float* __restrict__ dvb) {
  __shared__ unsigned short sA[2][128 * 64];
  __shared__ unsigned short sB[2][128 * 64];
  const int bx = blockIdx.x;
  int sel, rblk;
  const unsigned short* A;
  if (bx < 384) { sel = bx >> 7; rblk = bx & 127; A = hb; }
  else { sel = 3; rblk = bx - 384; A = rb; }
  const unsigned short* Bt = sel == 0 ? wq_t : (sel == 1 ? wk_t : (sel == 2 ? wv_t : wr_t));
  const int n0 = (rblk & 7) * 128, m0 = (rblk >> 3) * 128;
  const int tid = threadIdx.x, lane = tid & 63, w = tid >> 6;
  const int wm = w >> 1, wn = w & 1, g = lane >> 4, lc = lane & 15;

  f32x4 acc[2][4] = {};

  auto STAGE = [&](int buf, int kt) {
#pragma unroll
    for (int s = 0; s < 2; ++s) {
      int c = s * 512 + tid;
      int row = c >> 3;
      int ko = ((c & 7) ^ (row & 7)) * 8;
      int lbase = (s * 512 + w * 64) * 8;
      gload16(&A[(size_t)(m0 + row) * 1024 + kt + ko], &sA[buf][lbase]);
      gload16(&Bt[(size_t)(n0 + row) * 1024 + kt + ko], &sB[buf][lbase]);
    }
  };

  STAGE(0, 0);
  __syncthreads();

  for (int kt = 0; kt < 1024; kt += 64) {
    const int cur = (kt >> 6) & 1;
    if (kt < 960) STAGE(cur ^ 1, kt + 64);
    bf16x8 af[2][2], bfr[4][2];
#pragma unroll
    for (int ks = 0; ks < 2; ++ks) {
#pragma unroll
      for (int mi = 0; mi < 2; ++mi) {
        int ra = wm * 32 + mi * 16 + lc;
        af[mi][ks] = *(const bf16x8*)&sA[cur][ra * 64 + (((ks * 4 + g) ^ (ra & 7)) * 8)];
      }
#pragma unroll
      for (int ni = 0; ni < 4; ++ni) {
        int rb_ = wn * 64 + ni * 16 + lc;
        bfr[ni][ks] = *(const bf16x8*)&sB[cur][rb_ * 64 + (((ks * 4 + g) ^ (rb_ & 7)) * 8)];
      }
    }
#pragma unroll
    for (int ks = 0; ks < 2; ++ks)
#pragma unroll
      for (int mi = 0; mi < 2; ++mi)
#pragma unroll
        for (int ni = 0; ni < 4; ++ni)
          acc[mi][ni] = mfma16(af[mi][ks], bfr[ni][ks], acc[mi][ni]);
    __syncthreads();
  }

  if (sel == 0) {
    const int hn = (n0 >> 6) + wn;
    float sedv[4], bwv[4], brv[4], bsv[4];
#pragma unroll
    for (int ni = 0; ni < 4; ++ni) {
      int col = n0 + wn * 64 + ni * 16 + lc;
      sedv[ni] = seg_embed[1024 + hn * 64 + ni * 16 + lc] - seg_embed[hn * 64 + ni * 16 + lc];
      bwv[ni] = rwb[col];
      brv[ni] = rrb[col];
      bsv[ni] = rsb[col];
    }
#pragma unroll
    for (int mi = 0; mi < 2; ++mi) {
      int rowb = m0 + wm * 32 + mi * 16 + g * 4;
#pragma unroll
      for (int r = 0; r < 4; ++r) {
        float e = 0.f;
#pragma unroll
        for (int ni = 0; ni < 4; ++ni) {
          int col = n0 + wn * 64 + ni * 16 + lc;
          float v = acc[mi][ni][r];
          size_t idx = (size_t)(rowb + r) * 1024 + col;
          qwb[idx] = f2bf((v + bwv[ni]) * QSCL);
          qrb[idx] = f2bf((v + brv[ni]) * QSCL);
          e += (v + bsv[ni]) * 0.125f * sedv[ni];
        }
        e = rsum16(e);
        if (lc == 0) {
          int ib = rowb + r;
          int i = ib >> 1, b = ib & 1;
          dvb[(b * 16 + hn) * 1024 + i] = e * LOG2E;
        }
      }
    }
  } else {
#pragma unroll
    for (int ni = 0; ni < 4; ++ni) {
      int col = n0 + wn * 64 + ni * 16 + lc;
#pragma unroll
      for (int mi = 0; mi < 2; ++mi) {
        int rowb = m0 + wm * 32 + mi * 16 + g * 4;
#pragma unroll
        for (int r = 0; r < 4; ++r) {
          float v = acc[mi][ni][r];
          size_t idx = (size_t)(rowb + r) * 1024 + col;
          if (sel == 1) khb[idx] = f2bf(v);
          else if (sel == 2) vhb[idx] = f2bf(v);
          else krhb[idx] = f2bf(v);
        }
      }
    }
  }
}

// ---------------- out-projection: 64x128 tile, 8 waves, BK=64, 2-phase dbuf, swizzled ----------------
__global__ __launch_bounds__(512) void gemm64_out(const unsigned short* __restrict__ A,
                                                  const unsigned short* __restrict__ Bt,
                                                  float* __restrict__ C) {
  __shared__ unsigned short sA[2][64 * 64];
  __shared__ unsigned short sB[2][128 * 64];
  const int tid = threadIdx.x, lane = tid & 63, w = tid >> 6;
  const int wm = w >> 2, wn = w & 3, g = lane >> 4, lc = lane & 15;
  const int m0 = blockIdx.y * 64, n0 = blockIdx.x * 128;
  f32x4 acc[2][2] = {};

  auto STAGE = [&](int buf, int kt) {
    {
      int c = tid;
      int row = c >> 3;
      int ko = ((c & 7) ^ (row & 7)) * 8;
      gload16(&A[(size_t)(m0 + row) * 1024 + kt + ko], &sA[buf][w * 64 * 8]);
    }
#pragma unroll
    for (int s = 0; s < 2; ++s) {
      int c = s * 512 + tid;
      int row = c >> 3;
      int ko = ((c & 7) ^ (row & 7)) * 8;
      gload16(&Bt[(size_t)(n0 + row) * 1024 + kt + ko], &sB[buf][(s * 512 + w * 64) * 8]);
    }
  };

  STAGE(0, 0);
  __syncthreads();

  for (int kt = 0; kt < 1024; kt += 64) {
    const int cur = (kt >> 6) & 1;
    if (kt < 960) STAGE(cur ^ 1, kt + 64);
    bf16x8 af[2][2], bfr[2][2];
#pragma unroll
    for (int ks = 0; ks < 2; ++ks) {
#pragma unroll
      for (int mi = 0; mi < 2; ++mi) {
        int ra = wm * 32 + mi * 16 + lc;
        af[mi][ks] = *(const bf16x8*)&sA[cur][ra * 64 + (((ks * 4 + g) ^ (ra & 7)) * 8)];
      }
#pragma unroll
      for (int ni = 0; ni < 2; ++ni) {
        int rb_ = wn * 32 + ni * 16 + lc;
        bfr[ni][ks] = *(const bf16x8*)&sB[cur][rb_ * 64 + (((ks * 4 + g) ^ (rb_ & 7)) * 8)];
      }
    }
#pragma unroll
    for (int ks = 0; ks < 2; ++ks)
#pragma unroll
      for (int mi = 0; mi < 2; ++mi)
#pragma unroll
        for (int ni = 0; ni < 2; ++ni)
          acc[mi][ni] = mfma16(af[mi][ks], bfr[ni][ks], acc[mi][ni]);
    __syncthreads();
  }
#pragma unroll
  for (int ni = 0; ni < 2; ++ni) {
    int col = n0 + wn * 32 + ni * 16 + lc;
#pragma unroll
    for (int mi = 0; mi < 2; ++mi) {
      int rowb = m0 + wm * 32 + mi * 16 + g * 4;
#pragma unroll
      for (int r = 0; r < 4; ++r)
        C[(size_t)(rowb + r) * 1024 + col] = acc[mi][ni][r];
    }
  }
}

// ---------------- V transpose ----------------
__global__ __launch_bounds__(256) void transpose_v(const unsigned short* __restrict__ vh,
                                                   unsigned short* __restrict__ vT) {
  __shared__ unsigned short t[64][65];
  const int bn = blockIdx.y, j0 = blockIdx.x * 64;
  const int b = bn >> 4, n = bn & 15;
  const int r = threadIdx.x >> 4;
  const int c4 = (threadIdx.x & 15) * 4;
#pragma unroll
  for (int s = 0; s < 4; ++s) {
    int j = r + s * 16;
    us4 v = *(const us4*)&vh[((size_t)(j0 + j) * 2 + b) * 1024 + n * 64 + c4];
    t[j][c4 + 0] = v[0]; t[j][c4 + 1] = v[1]; t[j][c4 + 2] = v[2]; t[j][c4 + 3] = v[3];
  }
  __syncthreads();
#pragma unroll
  for (int s = 0; s < 4; ++s) {
    int d = r + s * 16;
    us4 v;
    v[0] = t[c4 + 0][d]; v[1] = t[c4 + 1][d]; v[2] = t[c4 + 2][d]; v[3] = t[c4 + 3][d];
    *(us4*)&vT[((size_t)bn * 64 + d) * 1024 + j0 + c4] = v;
  }
}

// ---------------- fused relative attention: R14 structure; LDS 64-stride + chunk-XOR (proj4-proven) ----------------
__global__ __launch_bounds__(512, 4) void attn_kernel(
    const unsigned short* __restrict__ qw, const unsigned short* __restrict__ qr,
    const unsigned short* __restrict__ kh, const unsigned short* __restrict__ krh,
    const unsigned short* __restrict__ vT,
    const float* __restrict__ dvb,
    const unsigned int* __restrict__ segmask,
    unsigned short* __restrict__ part, float* __restrict__ ml) {
  __shared__ unsigned short sK[64][64];    // chunk-XOR swizzled (key = row&7)
  __shared__ unsigned short sVT[64][64];   // chunk-XOR swizzled
  __shared__ unsigned short sKR[256][64];  // circular band, slot = jr & 255, chunk-XOR (key = jr&7)
  __shared__ unsigned short sP[8][16][80];

  const int tid = threadIdx.x, lane = tid & 63, w = tid >> 6;
  const int g = lane >> 4, lc = lane & 15;
  const int bn = blockIdx.x, b = bn >> 4, n = bn & 15;
  const int i0 = blockIdx.y * 128;
  const int js = blockIdx.z;
  const int S0 = 1024 + js * 512 - i0 - 127;

  bf16x8 fqw[2], fqr[2];
  const int qrow = i0 + w * 16 + lc;
#pragma unroll
  for (int ks = 0; ks < 2; ++ks) {
    size_t off = ((size_t)qrow * 2 + b) * 1024 + n * 64 + ks * 32 + g * 8;
    fqw[ks] = *(const bf16x8*)&qw[off];
    fqr[ks] = *(const bf16x8*)&qr[off];
  }
  float dv[4];
  unsigned int smoff[4];
#pragma unroll
  for (int r = 0; r < 4; ++r) {
    int i = i0 + w * 16 + g * 4 + r;
    dv[r] = dvb[bn * 1024 + i];
    smoff[r] = ((unsigned)b << 20) | ((unsigned)i << 10) | (unsigned)lc;
  }
  float mrun[4], lsum[4];
  f32x4 accO[4] = {};
#pragma unroll
  for (int r = 0; r < 4; ++r) { mrun[r] = -3e38f; lsum[r] = 0.f; }

  const int srow = tid >> 3;
  const int pchk = tid & 7;                        // physical LDS chunk (dest)
  const int skoK = ((pchk ^ (srow & 7))) * 8;      // pre-permuted global chunk for sK/sVT
  const int skoR = ((pchk ^ ((S0 + srow) & 7))) * 8;  // for sKR (row key = jr&7 = (S0+srow)&7)
  const int ldst = pchk * 8;                       // linear LDS chunk offset

#pragma unroll
  for (int pp = 0; pp < 3; ++pp) {
    int jr = S0 + pp * 64 + srow;
    *(uint4*)&sKR[jr & 255][ldst] =
        *(const uint4*)&krh[((size_t)jr * 2 + b) * 1024 + n * 64 + skoR];
  }
  int j0 = js * 512;
  uint4 rK = *(const uint4*)&kh[((size_t)(j0 + srow) * 2 + b) * 1024 + n * 64 + skoK];
  uint4 rV = *(const uint4*)&vT[((size_t)bn * 64 + srow) * 1024 + j0 + skoK];
  uint4 rR = *(const uint4*)&krh[((size_t)(S0 + 192 + srow) * 2 + b) * 1024 + n * 64 + skoR];

  for (int t = 0; t < 8; ++t) {
    j0 = (js * 8 + t) * 64;
    __syncthreads();
    *(uint4*)&sK[srow][ldst] = rK;
    *(uint4*)&sVT[srow][ldst] = rV;
    if (t < 7) {
      *(uint4*)&sKR[(S0 + 192 + t * 64 + srow) & 255][ldst] = rR;
      int j0n = j0 + 64;
      rK = *(const uint4*)&kh[((size_t)(j0n + srow) * 2 + b) * 1024 + n * 64 + skoK];
      rV = *(const uint4*)&vT[((size_t)bn * 64 + srow) * 1024 + j0n + skoK];
      if (t < 6) {
        int jr = S0 + 256 + t * 64 + srow;
        if (jr > 2047) jr = 2047;
        rR = *(const uint4*)&krh[((size_t)jr * 2 + b) * 1024 + n * 64 + skoR];
      }
    }
    unsigned int msv[4][4];
#pragma unroll
    for (int r = 0; r < 4; ++r)
#pragma unroll
      for (int nf = 0; nf < 4; ++nf)
        msv[r][nf] = segmask[smoff[r] + j0 + nf * 16];
    __syncthreads();

    const int base = S0 + t * 64 + (7 - w) * 16;
    const int krk = (S0 + lc) & 7;  // sKR read key: (base + k*16 + lc) & 7, base-lc terms mult of 8
    f32x4 bdk[5];
#pragma unroll
    for (int k = 0; k < 5; ++k) {
      f32x4 a = {0.f, 0.f, 0.f, 0.f};
#pragma unroll
      for (int ks = 0; ks < 2; ++ks) {
        bf16x8 fk = *(const bf16x8*)&sKR[(base + k * 16 + lc) & 255][(((ks * 4 + g) ^ krk)) * 8];
        a = mfma16(fqr[ks], fk, a);
      }
      bdk[k] = a;
    }
    float p[4][4];
#pragma unroll
    for (int r = 0; r < 4; ++r) {
      const int a_ = g * 4 + r;
      const int srcl = (lane & 48) | ((lc + 15 - a_) & 15);
      float s0 = __shfl(bdk[0][r], srcl);
      float s1 = __shfl(bdk[1][r], srcl);
      float s2 = __shfl(bdk[2][r], srcl);
      float s3 = __shfl(bdk[3][r], srcl);
      float s4 = __shfl(bdk[4][r], srcl);
      const bool lo = lc <= a_;
#pragma unroll
      for (int nf = 0; nf < 4; ++nf) {
        unsigned int u = msv[r][nf];
        float sgd = (u & 0xffffu) ? dv[r] : 0.f;
        float mkv = bf2f((unsigned short)(u >> 16));
        float bdv = lo ? (nf == 0 ? s0 : nf == 1 ? s1 : nf == 2 ? s2 : s3)
                       : (nf == 0 ? s1 : nf == 1 ? s2 : nf == 2 ? s3 : s4);
        p[r][nf] = sgd + mkv + bdv;
      }
    }
    f32x4 aa[4];
#pragma unroll
    for (int nf = 0; nf < 4; ++nf) {
      const int lk = lc & 7;  // sK read key: (nf*16+lc)&7 = lc&7
      f32x4 a = {0.f, 0.f, 0.f, 0.f};
#pragma unroll
      for (int ks = 0; ks < 2; ++ks) {
        bf16x8 fk = *(const bf16x8*)&sK[nf * 16 + lc][(((ks * 4 + g) ^ lk)) * 8];
        a = mfma16(fqw[ks], fk, a);
      }
      aa[nf] = a;
    }
#pragma unroll
    for (int r = 0; r < 4; ++r)
#pragma unroll
      for (int nf = 0; nf < 4; ++nf) p[r][nf] += aa[nf][r];

#pragma unroll
    for (int r = 0; r < 4; ++r) {
      float mt = fmaxf(fmaxf(p[r][0], p[r][1]), fmaxf(p[r][2], p[r][3]));
      mt = rmax16(mt);
      float mnew = fmaxf(mrun[r], mt);
      float corr = fexp2(mrun[r] - mnew);
      mrun[r] = mnew;
      float se = 0.f;
#pragma unroll
      for (int nf = 0; nf < 4; ++nf) {
        float e = fexp2(p[r][nf] - mnew);
        p[r][nf] = e;
        se += e;
      }
      se = rsum16(se);
      lsum[r] = lsum[r] * corr + se;
#pragma unroll
      for (int df = 0; df < 4; ++df) accO[df][r] *= corr;
#pragma unroll
      for (int nf = 0; nf < 4; ++nf)
        sP[w][g * 4 + r][nf * 16 + lc] = f2bf(p[r][nf]);
    }
#pragma unroll
    for (int ks = 0; ks < 2; ++ks) {
      bf16x8 fp = *(const bf16x8*)&sP[w][lc][ks * 32 + g * 8];
#pragma unroll
      for (int df = 0; df < 4; ++df) {
        const int vk = lc & 7;  // sVT read key
        bf16x8 fv = *(const bf16x8*)&sVT[df * 16 + lc][(((ks * 4 + g) ^ vk)) * 8];
        accO[df] = mfma16(fp, fv, accO[df]);
      }
    }
  }
#pragma unroll
  for (int r = 0; r < 4; ++r) {
    int i = i0 + w * 16 + g * 4 + r;
    size_t pb = ((size_t)(js * 32 + bn) * 1024 + i) * 64;
#pragma unroll
    for (int df = 0; df < 4; ++df) part[pb + df * 16 + lc] = f2bf(accO[df][r]);
    if (lc == 0) {
      size_t mb = (((size_t)js * 32 + bn) * 1024 + i) * 2;
      ml[mb] = mrun[r];
      ml[mb + 1] = lsum[r];
    }
  }
}

// ---------------- combine the two j-splits (exp2 basis, bf16 partials) ----------------
__global__ __launch_bounds__(256) void combine_kernel(const unsigned short* __restrict__ part,
                                                      const float* __restrict__ ml,
                                                      unsigned short* __restrict__ av) {
  int gw = blockIdx.x * 4 + (threadIdx.x >> 6);
  int lane = threadIdx.x & 63;
  int bn = gw >> 10, i = gw & 1023;
  int b = bn >> 4, n = bn & 15;
  float m0 = ml[((size_t)bn * 1024 + i) * 2];
  float l0 = ml[((size_t)bn * 1024 + i) * 2 + 1];
  float m1 = ml[(((size_t)32 + bn) * 1024 + i) * 2];
  float l1 = ml[(((size_t)32 + bn) * 1024 + i) * 2 + 1];
  float mx = fmaxf(m0, m1);
  float w0 = fexp2(m0 - mx), w1 = fexp2(m1 - mx);
  float inv = 1.f / (l0 * w0 + l1 * w1);
  float o = bf2f(part[((size_t)bn * 1024 + i) * 64 + lane]) * w0 +
            bf2f(part[(((size_t)32 + bn) * 1024 + i) * 64 + lane]) * w1;
  av[((size_t)i * 2 + b) * 1024 + n * 64 + lane] = f2bf(o * inv);
}

// ---------------- residual + LayerNorm ----------------
__global__ __launch_bounds__(256) void ln_kernel(const float* __restrict__ gout,
                                                 const float* __restrict__ h,
                                                 const float* __restrict__ gamma,
                                                 const float* __restrict__ beta,
                                                 float* __restrict__ out) {
  __shared__ float red[8];
  const int row = blockIdx.x;
  const int tid = threadIdx.x;
  float x[4];
  float s = 0.f;
#pragma unroll
  for (int q = 0; q < 4; ++q) {
    int d = tid + q * 256;
    x[q] = gout[(size_t)row * 1024 + d] + h[(size_t)row * 1024 + d];
    s += x[q];
  }
#pragma unroll
  for (int m = 1; m < 64; m <<= 1) s += __shfl_xor(s, m);
  if ((tid & 63) == 0) red[tid >> 6] = s;
  __syncthreads();
  s = red[0] + red[1] + red[2] + red[3];
  float mu = s * (1.f / 1024.f);
  float v = 0.f;
#pragma unroll
  for (int q = 0; q < 4; ++q) {
    float dd = x[q] - mu;
    v += dd * dd;
  }
#pragma unroll
  for (int m = 1; m < 64; m <<= 1) v += __shfl_xor(v, m);
  if ((tid & 63) == 0) red[4 + (tid >> 6)] = v;
  __syncthreads();
  v = red[4] + red[5] + red[6] + red[7];
  float rstd = rsqrtf(v * (1.f / 1024.f) + 1e-12f);
#pragma unroll
  for (int q = 0; q < 4; ++q) {
    int d = tid + q * 256;
    out[(size_t)row * 1024 + d] = (x[q] - mu) * rstd * gamma[d] + beta[d];
  }
}

extern "C" void kernel_launch(void* const* d_in, const int* in_sizes, int n_in,
                              void* d_out, int out_size, void* d_ws, size_t ws_size,
                              hipStream_t stream) {
  const float* h = (const float*)d_in[0];
  const float* r = (const float*)d_in[1];
  const unsigned char* seg = (const unsigned char*)d_in[2];
  const float* mask = (const float*)d_in[3];
  const float* wq = (const float*)d_in[4];
  const float* wk = (const float*)d_in[5];
  const float* wv = (const float*)d_in[6];
  const float* wr = (const float*)d_in[7];
  const float* wo = (const float*)d_in[8];
  const float* rwb = (const float*)d_in[9];
  const float* rrb = (const float*)d_in[10];
  const float* rsb = (const float*)d_in[11];
  const float* seg_embed = (const float*)d_in[12];
  const float* gamma = (const float*)d_in[13];
  const float* beta = (const float*)d_in[14];
  float* out = (float*)d_out;

  char* ws = (char*)d_ws;
  size_t off = 0;
  auto alloc = [&](size_t bytes) {
    size_t cur = off;
    off = (off + bytes + 255) & ~(size_t)255;
    return cur;
  };
  unsigned short* hb = (unsigned short*)(ws + alloc(2048 * 1024 * 2));
  unsigned short* rb = (unsigned short*)(ws + alloc(4096 * 1024 * 2));
  unsigned short* wq_t = (unsigned short*)(ws + alloc(1024 * 1024 * 2));
  unsigned short* wk_t = (unsigned short*)(ws + alloc(1024 * 1024 * 2));
  unsigned short* wv_t = (unsigned short*)(ws + alloc(1024 * 1024 * 2));
  unsigned short* wr_t = (unsigned short*)(ws + alloc(1024 * 1024 * 2));
  unsigned short* wo_b = (unsigned short*)(ws + alloc(1024 * 1024 * 2));
  unsigned short* qwb = (unsigned short*)(ws + alloc(2048 * 1024 * 2));
  unsigned short* qrb = (unsigned short*)(ws + alloc(2048 * 1024 * 2));
  unsigned short* khb = (unsigned short*)(ws + alloc(2048 * 1024 * 2));
  unsigned short* vhb = (unsigned short*)(ws + alloc(2048 * 1024 * 2));
  unsigned short* krhb = (unsigned short*)(ws + alloc(4096 * 1024 * 2));
  unsigned short* vTb = (unsigned short*)(ws + alloc(2048 * 1024 * 2));
  float* dvb = (float*)(ws + alloc(2048 * 16 * 4));
  unsigned int* segmask = (unsigned int*)(ws + alloc(2 * 1024 * 1024 * 4));
  unsigned short* avb = (unsigned short*)(ws + alloc(2048 * 1024 * 2));
  float* gout = (float*)(ws + alloc(2048 * 1024 * 4));
  unsigned short* part = (unsigned short*)(ws + alloc((size_t)2 * 32 * 1024 * 64 * 2));
  float* mlb = (float*)(ws + alloc((size_t)2 * 32 * 1024 * 2 * 4));
  (void)ws_size; (void)in_sizes; (void)n_in; (void)out_size;

  pre_kernel<<<15360, 256, 0, stream>>>(h, r, wo, wq, wk, wv, wr, seg, mask,
                                        hb, rb, wo_b, wq_t, wk_t, wv_t, wr_t, segmask);

  proj4_kernel<<<640, 512, 0, stream>>>(hb, rb, wq_t, wk_t, wv_t, wr_t, rwb, rrb, rsb,
                                        seg_embed, qwb, qrb, khb, vhb, krhb, dvb);

  transpose_v<<<dim3(16, 32), 256, 0, stream>>>(vhb, vTb);

  attn_kernel<<<dim3(32, 8, 2), 512, 0, stream>>>(qwb, qrb, khb, krhb, vTb,
                                                  dvb, segmask, part, mlb);
  combine_kernel<<<8192, 256, 0, stream>>>(part, mlb, avb);

  gemm64_out<<<dim3(8, 32), 512, 0, stream>>>(avb, wo_b, gout);
  ln_kernel<<<2048, 256, 0, stream>>>(gout, h, gamma, beta, out);
}

// Round 16
// 120.581 us; speedup vs baseline: 1.4276x; 1.0428x over previous
//
#include <hip/hip_runtime.h>

typedef __bf16 bf16x8 __attribute__((ext_vector_type(8)));
typedef float f32x4 __attribute__((ext_vector_type(4)));
typedef unsigned short us4 __attribute__((ext_vector_type(4)));

__device__ __forceinline__ unsigned short f2bf(float f) {
  unsigned int u = __builtin_bit_cast(unsigned int, f);
  u += 0x7fffu + ((u >> 16) & 1u);
  return (unsigned short)(u >> 16);
}
__device__ __forceinline__ float bf2f(unsigned short s) {
  unsigned int u = ((unsigned int)s) << 16;
  return __builtin_bit_cast(float, u);
}
__device__ __forceinline__ f32x4 mfma16(bf16x8 a, bf16x8 b, f32x4 c) {
  return __builtin_amdgcn_mfma_f32_16x16x32_bf16(a, b, c, 0, 0, 0);
}
__device__ __forceinline__ void gload16(const void* g, void* l) {
  __builtin_amdgcn_global_load_lds(
      (const __attribute__((address_space(1))) unsigned int*)g,
      (__attribute__((address_space(3))) unsigned int*)l, 16, 0, 0);
}
__device__ __forceinline__ float fexp2(float x) {
  float r;
  asm("v_exp_f32 %0, %1" : "=v"(r) : "v"(x));
  return r;
}
template <int CTRL>
__device__ __forceinline__ float dppf(float x) {
  return __builtin_bit_cast(
      float, __builtin_amdgcn_mov_dpp(__builtin_bit_cast(int, x), CTRL, 0xf, 0xf, true));
}
__device__ __forceinline__ float rsum16(float x) {
  x += dppf<0xB1>(x);
  x += dppf<0x4E>(x);
  x += dppf<0x124>(x);
  x += dppf<0x128>(x);
  return x;
}

#define QSCL 0.18033688011112042f  /* 0.125 * log2(e) */
#define LOG2E 1.4426950408889634f
#define SHIFT 16.0f                /* fixed softmax shift (log2 basis), folded into mask */

// ---------------- fused preprocessing: casts + weight transposes + segmask, one launch ----------------
__global__ __launch_bounds__(256) void pre_kernel(
    const float* __restrict__ h, const float* __restrict__ r, const float* __restrict__ wo,
    const float* __restrict__ w0, const float* __restrict__ w1,
    const float* __restrict__ w2, const float* __restrict__ w3,
    const unsigned char* __restrict__ seg, const float* __restrict__ mask,
    unsigned short* __restrict__ hb, unsigned short* __restrict__ rb,
    unsigned short* __restrict__ wo_b,
    unsigned short* __restrict__ o0, unsigned short* __restrict__ o1,
    unsigned short* __restrict__ o2, unsigned short* __restrict__ o3,
    unsigned int* __restrict__ segout) {
  __shared__ float t[32][33];
  const int bx = blockIdx.x;
  const int tid = threadIdx.x;
  if (bx < 7168) {
    int idx = bx * 256 + tid;
    const float* in;
    unsigned short* out;
    int o;
    if (idx < 524288) { in = h; out = hb; o = idx; }
    else if (idx < 1572864) { in = r; out = rb; o = idx - 524288; }
    else { in = wo; out = wo_b; o = idx - 1572864; }
    float4 v = ((const float4*)in)[o];
    us4 tt;
    tt[0] = f2bf(v.x); tt[1] = f2bf(v.y); tt[2] = f2bf(v.z); tt[3] = f2bf(v.w);
    *(us4*)&out[o * 4] = tt;
  } else if (bx < 11264) {
    int zz = bx - 7168;
    int z = zz >> 10, tt_ = zz & 1023;
    const float* in = z == 0 ? w0 : (z == 1 ? w1 : (z == 2 ? w2 : w3));
    unsigned short* out = z == 0 ? o0 : (z == 1 ? o1 : (z == 2 ? o2 : o3));
    int k0 = (tt_ >> 5) * 32;
    int n0 = (tt_ & 31) * 32;
    int rr = tid >> 5;
    int c = tid & 31;
#pragma unroll
    for (int s = 0; s < 4; ++s)
      t[rr + s * 8][c] = in[(k0 + rr + s * 8) * 1024 + n0 + c];
    __syncthreads();
#pragma unroll
    for (int s = 0; s < 4; ++s)
      out[(n0 + rr + s * 8) * 1024 + k0 + c] = f2bf(t[c][rr + s * 8]);
  } else {
    int ij = (bx - 11264) * 256 + tid;
    unsigned short sv = *(const unsigned short*)&seg[ij * 2];
    float2 mv = *(const float2*)&mask[(size_t)ij * 2];
    // mask pre-scaled by log2e, with fixed softmax shift folded in:
    // unmasked -> -SHIFT, masked -> ~-1.44e30 (bf16-identical)
    unsigned int q0 = ((unsigned int)f2bf(mv.x * -1.4426950408889634e30f - SHIFT) << 16) |
                      ((sv & 0xffu) ? 0x3f80u : 0u);
    unsigned int q1 = ((unsigned int)f2bf(mv.y * -1.4426950408889634e30f - SHIFT) << 16) |
                      ((sv >> 8) ? 0x3f80u : 0u);
    segout[ij] = q0;
    segout[1048576 + ij] = q1;
  }
}

// ---------------- all 4 projections (R7 structure) + fused dv epilogue ----------------
__global__ __launch_bounds__(512) void proj4_kernel(
    const unsigned short* __restrict__ hb, const unsigned short* __restrict__ rb,
    const unsigned short* __restrict__ wq_t, const unsigned short* __restrict__ wk_t,
    const unsigned short* __restrict__ wv_t, const unsigned short* __restrict__ wr_t,
    const float* __restrict__ rwb, const float* __restrict__ rrb, const float* __restrict__ rsb,
    const float* __restrict__ seg_embed,
    unsigned short* __restrict__ qwb, unsigned short* __restrict__ qrb,
    unsigned short* __restrict__ khb, unsigned short* __restrict__ vhb,
    unsigned short* __restrict__ krhb,
    float* __restrict__ dvb) {
  __shared__ unsigned short sA[2][128 * 64];
  __shared__ unsigned short sB[2][128 * 64];
  const int bx = blockIdx.x;
  int sel, rblk;
  const unsigned short* A;
  if (bx < 384) { sel = bx >> 7; rblk = bx & 127; A = hb; }
  else { sel = 3; rblk = bx - 384; A = rb; }
  const unsigned short* Bt = sel == 0 ? wq_t : (sel == 1 ? wk_t : (sel == 2 ? wv_t : wr_t));
  const int n0 = (rblk & 7) * 128, m0 = (rblk >> 3) * 128;
  const int tid = threadIdx.x, lane = tid & 63, w = tid >> 6;
  const int wm = w >> 1, wn = w & 1, g = lane >> 4, lc = lane & 15;

  f32x4 acc[2][4] = {};

  auto STAGE = [&](int buf, int kt) {
#pragma unroll
    for (int s = 0; s < 2; ++s) {
      int c = s * 512 + tid;
      int row = c >> 3;
      int ko = ((c & 7) ^ (row & 7)) * 8;
      int lbase = (s * 512 + w * 64) * 8;
      gload16(&A[(size_t)(m0 + row) * 1024 + kt + ko], &sA[buf][lbase]);
      gload16(&Bt[(size_t)(n0 + row) * 1024 + kt + ko], &sB[buf][lbase]);
    }
  };

  STAGE(0, 0);
  __syncthreads();

  for (int kt = 0; kt < 1024; kt += 64) {
    const int cur = (kt >> 6) & 1;
    if (kt < 960) STAGE(cur ^ 1, kt + 64);
    bf16x8 af[2][2], bfr[4][2];
#pragma unroll
    for (int ks = 0; ks < 2; ++ks) {
#pragma unroll
      for (int mi = 0; mi < 2; ++mi) {
        int ra = wm * 32 + mi * 16 + lc;
        af[mi][ks] = *(const bf16x8*)&sA[cur][ra * 64 + (((ks * 4 + g) ^ (ra & 7)) * 8)];
      }
#pragma unroll
      for (int ni = 0; ni < 4; ++ni) {
        int rb_ = wn * 64 + ni * 16 + lc;
        bfr[ni][ks] = *(const bf16x8*)&sB[cur][rb_ * 64 + (((ks * 4 + g) ^ (rb_ & 7)) * 8)];
      }
    }
#pragma unroll
    for (int ks = 0; ks < 2; ++ks)
#pragma unroll
      for (int mi = 0; mi < 2; ++mi)
#pragma unroll
        for (int ni = 0; ni < 4; ++ni)
          acc[mi][ni] = mfma16(af[mi][ks], bfr[ni][ks], acc[mi][ni]);
    __syncthreads();
  }

  if (sel == 0) {
    const int hn = (n0 >> 6) + wn;
    float sedv[4], bwv[4], brv[4], bsv[4];
#pragma unroll
    for (int ni = 0; ni < 4; ++ni) {
      int col = n0 + wn * 64 + ni * 16 + lc;
      sedv[ni] = seg_embed[1024 + hn * 64 + ni * 16 + lc] - seg_embed[hn * 64 + ni * 16 + lc];
      bwv[ni] = rwb[col];
      brv[ni] = rrb[col];
      bsv[ni] = rsb[col];
    }
#pragma unroll
    for (int mi = 0; mi < 2; ++mi) {
      int rowb = m0 + wm * 32 + mi * 16 + g * 4;
#pragma unroll
      for (int r = 0; r < 4; ++r) {
        float e = 0.f;
#pragma unroll
        for (int ni = 0; ni < 4; ++ni) {
          int col = n0 + wn * 64 + ni * 16 + lc;
          float v = acc[mi][ni][r];
          size_t idx = (size_t)(rowb + r) * 1024 + col;
          qwb[idx] = f2bf((v + bwv[ni]) * QSCL);
          qrb[idx] = f2bf((v + brv[ni]) * QSCL);
          e += (v + bsv[ni]) * 0.125f * sedv[ni];
        }
        e = rsum16(e);
        if (lc == 0) {
          int ib = rowb + r;
          int i = ib >> 1, b = ib & 1;
          dvb[(b * 16 + hn) * 1024 + i] = e * LOG2E;
        }
      }
    }
  } else {
#pragma unroll
    for (int ni = 0; ni < 4; ++ni) {
      int col = n0 + wn * 64 + ni * 16 + lc;
#pragma unroll
      for (int mi = 0; mi < 2; ++mi) {
        int rowb = m0 + wm * 32 + mi * 16 + g * 4;
#pragma unroll
        for (int r = 0; r < 4; ++r) {
          float v = acc[mi][ni][r];
          size_t idx = (size_t)(rowb + r) * 1024 + col;
          if (sel == 1) khb[idx] = f2bf(v);
          else if (sel == 2) vhb[idx] = f2bf(v);
          else krhb[idx] = f2bf(v);
        }
      }
    }
  }
}

// ---------------- out-projection: 64x128 tile, 8 waves, BK=64, 2-phase dbuf, swizzled ----------------
__global__ __launch_bounds__(512) void gemm64_out(const unsigned short* __restrict__ A,
                                                  const unsigned short* __restrict__ Bt,
                                                  float* __restrict__ C) {
  __shared__ unsigned short sA[2][64 * 64];
  __shared__ unsigned short sB[2][128 * 64];
  const int tid = threadIdx.x, lane = tid & 63, w = tid >> 6;
  const int wm = w >> 2, wn = w & 3, g = lane >> 4, lc = lane & 15;
  const int m0 = blockIdx.y * 64, n0 = blockIdx.x * 128;
  f32x4 acc[2][2] = {};

  auto STAGE = [&](int buf, int kt) {
    {
      int c = tid;
      int row = c >> 3;
      int ko = ((c & 7) ^ (row & 7)) * 8;
      gload16(&A[(size_t)(m0 + row) * 1024 + kt + ko], &sA[buf][w * 64 * 8]);
    }
#pragma unroll
    for (int s = 0; s < 2; ++s) {
      int c = s * 512 + tid;
      int row = c >> 3;
      int ko = ((c & 7) ^ (row & 7)) * 8;
      gload16(&Bt[(size_t)(n0 + row) * 1024 + kt + ko], &sB[buf][(s * 512 + w * 64) * 8]);
    }
  };

  STAGE(0, 0);
  __syncthreads();

  for (int kt = 0; kt < 1024; kt += 64) {
    const int cur = (kt >> 6) & 1;
    if (kt < 960) STAGE(cur ^ 1, kt + 64);
    bf16x8 af[2][2], bfr[2][2];
#pragma unroll
    for (int ks = 0; ks < 2; ++ks) {
#pragma unroll
      for (int mi = 0; mi < 2; ++mi) {
        int ra = wm * 32 + mi * 16 + lc;
        af[mi][ks] = *(const bf16x8*)&sA[cur][ra * 64 + (((ks * 4 + g) ^ (ra & 7)) * 8)];
      }
#pragma unroll
      for (int ni = 0; ni < 2; ++ni) {
        int rb_ = wn * 32 + ni * 16 + lc;
        bfr[ni][ks] = *(const bf16x8*)&sB[cur][rb_ * 64 + (((ks * 4 + g) ^ (rb_ & 7)) * 8)];
      }
    }
#pragma unroll
    for (int ks = 0; ks < 2; ++ks)
#pragma unroll
      for (int mi = 0; mi < 2; ++mi)
#pragma unroll
        for (int ni = 0; ni < 2; ++ni)
          acc[mi][ni] = mfma16(af[mi][ks], bfr[ni][ks], acc[mi][ni]);
    __syncthreads();
  }
#pragma unroll
  for (int ni = 0; ni < 2; ++ni) {
    int col = n0 + wn * 32 + ni * 16 + lc;
#pragma unroll
    for (int mi = 0; mi < 2; ++mi) {
      int rowb = m0 + wm * 32 + mi * 16 + g * 4;
#pragma unroll
      for (int r = 0; r < 4; ++r)
        C[(size_t)(rowb + r) * 1024 + col] = acc[mi][ni][r];
    }
  }
}

// ---------------- V transpose ----------------
__global__ __launch_bounds__(256) void transpose_v(const unsigned short* __restrict__ vh,
                                                   unsigned short* __restrict__ vT) {
  __shared__ unsigned short t[64][65];
  const int bn = blockIdx.y, j0 = blockIdx.x * 64;
  const int b = bn >> 4, n = bn & 15;
  const int r = threadIdx.x >> 4;
  const int c4 = (threadIdx.x & 15) * 4;
#pragma unroll
  for (int s = 0; s < 4; ++s) {
    int j = r + s * 16;
    us4 v = *(const us4*)&vh[((size_t)(j0 + j) * 2 + b) * 1024 + n * 64 + c4];
    t[j][c4 + 0] = v[0]; t[j][c4 + 1] = v[1]; t[j][c4 + 2] = v[2]; t[j][c4 + 3] = v[3];
  }
  __syncthreads();
#pragma unroll
  for (int s = 0; s < 4; ++s) {
    int d = r + s * 16;
    us4 v;
    v[0] = t[c4 + 0][d]; v[1] = t[c4 + 1][d]; v[2] = t[c4 + 2][d]; v[3] = t[c4 + 3][d];
    *(us4*)&vT[((size_t)bn * 64 + d) * 1024 + j0 + c4] = v;
  }
}

// ---------------- fused relative attention: R15 structure; fixed-shift softmax (no max tracking) ----------------
__global__ __launch_bounds__(512, 4) void attn_kernel(
    const unsigned short* __restrict__ qw, const unsigned short* __restrict__ qr,
    const unsigned short* __restrict__ kh, const unsigned short* __restrict__ krh,
    const unsigned short* __restrict__ vT,
    const float* __restrict__ dvb,
    const unsigned int* __restrict__ segmask,
    unsigned short* __restrict__ part, float* __restrict__ ml) {
  __shared__ unsigned short sK[64][64];    // chunk-XOR swizzled (key = row&7)
  __shared__ unsigned short sVT[64][64];   // chunk-XOR swizzled
  __shared__ unsigned short sKR[256][64];  // circular band, slot = jr & 255, chunk-XOR (key = jr&7)
  __shared__ unsigned short sP[8][16][72]; // stride 72: g-offset 144 dw = 16 mod 32 -> 2-way (free)

  const int tid = threadIdx.x, lane = tid & 63, w = tid >> 6;
  const int g = lane >> 4, lc = lane & 15;
  const int bn = blockIdx.x, b = bn >> 4, n = bn & 15;
  const int i0 = blockIdx.y * 128;
  const int js = blockIdx.z;
  const int S0 = 1024 + js * 512 - i0 - 127;

  bf16x8 fqw[2], fqr[2];
  const int qrow = i0 + w * 16 + lc;
#pragma unroll
  for (int ks = 0; ks < 2; ++ks) {
    size_t off = ((size_t)qrow * 2 + b) * 1024 + n * 64 + ks * 32 + g * 8;
    fqw[ks] = *(const bf16x8*)&qw[off];
    fqr[ks] = *(const bf16x8*)&qr[off];
  }
  float dv[4];
  unsigned int smoff[4];
#pragma unroll
  for (int r = 0; r < 4; ++r) {
    int i = i0 + w * 16 + g * 4 + r;
    dv[r] = dvb[bn * 1024 + i];
    smoff[r] = ((unsigned)b << 20) | ((unsigned)i << 10) | (unsigned)lc;
  }
  float lsum[4];
  f32x4 accO[4] = {};
#pragma unroll
  for (int r = 0; r < 4; ++r) lsum[r] = 0.f;

  const int srow = tid >> 3;
  const int pchk = tid & 7;
  const int skoK = ((pchk ^ (srow & 7))) * 8;
  const int skoR = ((pchk ^ ((S0 + srow) & 7))) * 8;
  const int ldst = pchk * 8;

#pragma unroll
  for (int pp = 0; pp < 3; ++pp) {
    int jr = S0 + pp * 64 + srow;
    *(uint4*)&sKR[jr & 255][ldst] =
        *(const uint4*)&krh[((size_t)jr * 2 + b) * 1024 + n * 64 + skoR];
  }
  int j0 = js * 512;
  uint4 rK = *(const uint4*)&kh[((size_t)(j0 + srow) * 2 + b) * 1024 + n * 64 + skoK];
  uint4 rV = *(const uint4*)&vT[((size_t)bn * 64 + srow) * 1024 + j0 + skoK];
  uint4 rR = *(const uint4*)&krh[((size_t)(S0 + 192 + srow) * 2 + b) * 1024 + n * 64 + skoR];

  for (int t = 0; t < 8; ++t) {
    j0 = (js * 8 + t) * 64;
    __syncthreads();
    *(uint4*)&sK[srow][ldst] = rK;
    *(uint4*)&sVT[srow][ldst] = rV;
    if (t < 7) {
      *(uint4*)&sKR[(S0 + 192 + t * 64 + srow) & 255][ldst] = rR;
      int j0n = j0 + 64;
      rK = *(const uint4*)&kh[((size_t)(j0n + srow) * 2 + b) * 1024 + n * 64 + skoK];
      rV = *(const uint4*)&vT[((size_t)bn * 64 + srow) * 1024 + j0n + skoK];
      if (t < 6) {
        int jr = S0 + 256 + t * 64 + srow;
        if (jr > 2047) jr = 2047;
        rR = *(const uint4*)&krh[((size_t)jr * 2 + b) * 1024 + n * 64 + skoR];
      }
    }
    unsigned int msv[4][4];
#pragma unroll
    for (int r = 0; r < 4; ++r)
#pragma unroll
      for (int nf = 0; nf < 4; ++nf)
        msv[r][nf] = segmask[smoff[r] + j0 + nf * 16];
    __syncthreads();

    const int base = S0 + t * 64 + (7 - w) * 16;
    const int krk = (S0 + lc) & 7;
    f32x4 bdk[5];
#pragma unroll
    for (int k = 0; k < 5; ++k) {
      f32x4 a = {0.f, 0.f, 0.f, 0.f};
#pragma unroll
      for (int ks = 0; ks < 2; ++ks) {
        bf16x8 fk = *(const bf16x8*)&sKR[(base + k * 16 + lc) & 255][(((ks * 4 + g) ^ krk)) * 8];
        a = mfma16(fqr[ks], fk, a);
      }
      bdk[k] = a;
    }
    float p[4][4];
#pragma unroll
    for (int r = 0; r < 4; ++r) {
      const int a_ = g * 4 + r;
      const int srcl = (lane & 48) | ((lc + 15 - a_) & 15);
      float s0 = __shfl(bdk[0][r], srcl);
      float s1 = __shfl(bdk[1][r], srcl);
      float s2 = __shfl(bdk[2][r], srcl);
      float s3 = __shfl(bdk[3][r], srcl);
      float s4 = __shfl(bdk[4][r], srcl);
      const bool lo = lc <= a_;
#pragma unroll
      for (int nf = 0; nf < 4; ++nf) {
        unsigned int u = msv[r][nf];
        float sgd = (u & 0xffffu) ? dv[r] : 0.f;
        float mkv = bf2f((unsigned short)(u >> 16));  // includes -SHIFT
        float bdv = lo ? (nf == 0 ? s0 : nf == 1 ? s1 : nf == 2 ? s2 : s3)
                       : (nf == 0 ? s1 : nf == 1 ? s2 : nf == 2 ? s3 : s4);
        p[r][nf] = sgd + mkv + bdv;
      }
    }
    f32x4 aa[4];
#pragma unroll
    for (int nf = 0; nf < 4; ++nf) {
      const int lk = lc & 7;
      f32x4 a = {0.f, 0.f, 0.f, 0.f};
#pragma unroll
      for (int ks = 0; ks < 2; ++ks) {
        bf16x8 fk = *(const bf16x8*)&sK[nf * 16 + lc][(((ks * 4 + g) ^ lk)) * 8];
        a = mfma16(fqw[ks], fk, a);
      }
      aa[nf] = a;
    }
#pragma unroll
    for (int r = 0; r < 4; ++r)
#pragma unroll
      for (int nf = 0; nf < 4; ++nf) p[r][nf] += aa[nf][r];

    // fixed-shift softmax accumulation (shift folded into mask constant)
#pragma unroll
    for (int r = 0; r < 4; ++r) {
      float se = 0.f;
#pragma unroll
      for (int nf = 0; nf < 4; ++nf) {
        float e = fexp2(p[r][nf]);
        p[r][nf] = e;
        se += e;
      }
      se = rsum16(se);
      lsum[r] += se;
#pragma unroll
      for (int nf = 0; nf < 4; ++nf)
        sP[w][g * 4 + r][nf * 16 + lc] = f2bf(p[r][nf]);
    }
#pragma unroll
    for (int ks = 0; ks < 2; ++ks) {
      bf16x8 fp = *(const bf16x8*)&sP[w][lc][ks * 32 + g * 8];
#pragma unroll
      for (int df = 0; df < 4; ++df) {
        const int vk = lc & 7;
        bf16x8 fv = *(const bf16x8*)&sVT[df * 16 + lc][(((ks * 4 + g) ^ vk)) * 8];
        accO[df] = mfma16(fp, fv, accO[df]);
      }
    }
  }
#pragma unroll
  for (int r = 0; r < 4; ++r) {
    int i = i0 + w * 16 + g * 4 + r;
    size_t pb = ((size_t)(js * 32 + bn) * 1024 + i) * 64;
#pragma unroll
    for (int df = 0; df < 4; ++df) part[pb + df * 16 + lc] = f2bf(accO[df][r]);
    if (lc == 0) ml[((size_t)js * 32 + bn) * 1024 + i] = lsum[r];
  }
}

// ---------------- combine the two j-splits (fixed-shift: plain sum) ----------------
__global__ __launch_bounds__(256) void combine_kernel(const unsigned short* __restrict__ part,
                                                      const float* __restrict__ ml,
                                                      unsigned short* __restrict__ av) {
  int gw = blockIdx.x * 4 + (threadIdx.x >> 6);
  int lane = threadIdx.x & 63;
  int bn = gw >> 10, i = gw & 1023;
  int b = bn >> 4, n = bn & 15;
  float l0 = ml[(size_t)bn * 1024 + i];
  float l1 = ml[((size_t)32 + bn) * 1024 + i];
  float inv = 1.f / (l0 + l1);
  float o = bf2f(part[((size_t)bn * 1024 + i) * 64 + lane]) +
            bf2f(part[(((size_t)32 + bn) * 1024 + i) * 64 + lane]);
  av[((size_t)i * 2 + b) * 1024 + n * 64 + lane] = f2bf(o * inv);
}

// ---------------- residual + LayerNorm ----------------
__global__ __launch_bounds__(256) void ln_kernel(const float* __restrict__ gout,
                                                 const float* __restrict__ h,
                                                 const float* __restrict__ gamma,
                                                 const float* __restrict__ beta,
                                                 float* __restrict__ out) {
  __shared__ float red[8];
  const int row = blockIdx.x;
  const int tid = threadIdx.x;
  float x[4];
  float s = 0.f;
#pragma unroll
  for (int q = 0; q < 4; ++q) {
    int d = tid + q * 256;
    x[q] = gout[(size_t)row * 1024 + d] + h[(size_t)row * 1024 + d];
    s += x[q];
  }
#pragma unroll
  for (int m = 1; m < 64; m <<= 1) s += __shfl_xor(s, m);
  if ((tid & 63) == 0) red[tid >> 6] = s;
  __syncthreads();
  s = red[0] + red[1] + red[2] + red[3];
  float mu = s * (1.f / 1024.f);
  float v = 0.f;
#pragma unroll
  for (int q = 0; q < 4; ++q) {
    float dd = x[q] - mu;
    v += dd * dd;
  }
#pragma unroll
  for (int m = 1; m < 64; m <<= 1) v += __shfl_xor(v, m);
  if ((tid & 63) == 0) red[4 + (tid >> 6)] = v;
  __syncthreads();
  v = red[4] + red[5] + red[6] + red[7];
  float rstd = rsqrtf(v * (1.f / 1024.f) + 1e-12f);
#pragma unroll
  for (int q = 0; q < 4; ++q) {
    int d = tid + q * 256;
    out[(size_t)row * 1024 + d] = (x[q] - mu) * rstd * gamma[d] + beta[d];
  }
}

extern "C" void kernel_launch(void* const* d_in, const int* in_sizes, int n_in,
                              void* d_out, int out_size, void* d_ws, size_t ws_size,
                              hipStream_t stream) {
  const float* h = (const float*)d_in[0];
  const float* r = (const float*)d_in[1];
  const unsigned char* seg = (const unsigned char*)d_in[2];
  const float* mask = (const float*)d_in[3];
  const float* wq = (const float*)d_in[4];
  const float* wk = (const float*)d_in[5];
  const float* wv = (const float*)d_in[6];
  const float* wr = (const float*)d_in[7];
  const float* wo = (const float*)d_in[8];
  const float* rwb = (const float*)d_in[9];
  const float* rrb = (const float*)d_in[10];
  const float* rsb = (const float*)d_in[11];
  const float* seg_embed = (const float*)d_in[12];
  const float* gamma = (const float*)d_in[13];
  const float* beta = (const float*)d_in[14];
  float* out = (float*)d_out;

  char* ws = (char*)d_ws;
  size_t off = 0;
  auto alloc = [&](size_t bytes) {
    size_t cur = off;
    off = (off + bytes + 255) & ~(size_t)255;
    return cur;
  };
  unsigned short* hb = (unsigned short*)(ws + alloc(2048 * 1024 * 2));
  unsigned short* rb = (unsigned short*)(ws + alloc(4096 * 1024 * 2));
  unsigned short* wq_t = (unsigned short*)(ws + alloc(1024 * 1024 * 2));
  unsigned short* wk_t = (unsigned short*)(ws + alloc(1024 * 1024 * 2));
  unsigned short* wv_t = (unsigned short*)(ws + alloc(1024 * 1024 * 2));
  unsigned short* wr_t = (unsigned short*)(ws + alloc(1024 * 1024 * 2));
  unsigned short* wo_b = (unsigned short*)(ws + alloc(1024 * 1024 * 2));
  unsigned short* qwb = (unsigned short*)(ws + alloc(2048 * 1024 * 2));
  unsigned short* qrb = (unsigned short*)(ws + alloc(2048 * 1024 * 2));
  unsigned short* khb = (unsigned short*)(ws + alloc(2048 * 1024 * 2));
  unsigned short* vhb = (unsigned short*)(ws + alloc(2048 * 1024 * 2));
  unsigned short* krhb = (unsigned short*)(ws + alloc(4096 * 1024 * 2));
  unsigned short* vTb = (unsigned short*)(ws + alloc(2048 * 1024 * 2));
  float* dvb = (float*)(ws + alloc(2048 * 16 * 4));
  unsigned int* segmask = (unsigned int*)(ws + alloc(2 * 1024 * 1024 * 4));
  unsigned short* avb = (unsigned short*)(ws + alloc(2048 * 1024 * 2));
  float* gout = (float*)(ws + alloc(2048 * 1024 * 4));
  unsigned short* part = (unsigned short*)(ws + alloc((size_t)2 * 32 * 1024 * 64 * 2));
  float* mlb = (float*)(ws + alloc((size_t)2 * 32 * 1024 * 4));
  (void)ws_size; (void)in_sizes; (void)n_in; (void)out_size;

  pre_kernel<<<15360, 256, 0, stream>>>(h, r, wo, wq, wk, wv, wr, seg, mask,
                                        hb, rb, wo_b, wq_t, wk_t, wv_t, wr_t, segmask);

  proj4_kernel<<<640, 512, 0, stream>>>(hb, rb, wq_t, wk_t, wv_t, wr_t, rwb, rrb, rsb,
                                        seg_embed, qwb, qrb, khb, vhb, krhb, dvb);

  transpose_v<<<dim3(16, 32), 256, 0, stream>>>(vhb, vTb);

  attn_kernel<<<dim3(32, 8, 2), 512, 0, stream>>>(qwb, qrb, khb, krhb, vTb,
                                                  dvb, segmask, part, mlb);
  combine_kernel<<<8192, 256, 0, stream>>>(part, mlb, avb);

  gemm64_out<<<dim3(8, 32), 512, 0, stream>>>(avb, wo_b, gout);
  ln_kernel<<<2048, 256, 0, stream>>>(gout, h, gamma, beta, out);
}

// Round 17
// 120.532 us; speedup vs baseline: 1.4282x; 1.0004x over previous
//
#include <hip/hip_runtime.h>

typedef __bf16 bf16x8 __attribute__((ext_vector_type(8)));
typedef float f32x4 __attribute__((ext_vector_type(4)));
typedef unsigned short us4 __attribute__((ext_vector_type(4)));

__device__ __forceinline__ unsigned short f2bf(float f) {
  unsigned int u = __builtin_bit_cast(unsigned int, f);
  u += 0x7fffu + ((u >> 16) & 1u);
  return (unsigned short)(u >> 16);
}
__device__ __forceinline__ float bf2f(unsigned short s) {
  unsigned int u = ((unsigned int)s) << 16;
  return __builtin_bit_cast(float, u);
}
__device__ __forceinline__ f32x4 mfma16(bf16x8 a, bf16x8 b, f32x4 c) {
  return __builtin_amdgcn_mfma_f32_16x16x32_bf16(a, b, c, 0, 0, 0);
}
__device__ __forceinline__ void gload16(const void* g, void* l) {
  __builtin_amdgcn_global_load_lds(
      (const __attribute__((address_space(1))) unsigned int*)g,
      (__attribute__((address_space(3))) unsigned int*)l, 16, 0, 0);
}
__device__ __forceinline__ float fexp2(float x) {
  float r;
  asm("v_exp_f32 %0, %1" : "=v"(r) : "v"(x));
  return r;
}
template <int CTRL>
__device__ __forceinline__ float dppf(float x) {
  return __builtin_bit_cast(
      float, __builtin_amdgcn_mov_dpp(__builtin_bit_cast(int, x), CTRL, 0xf, 0xf, true));
}
__device__ __forceinline__ float rsum16(float x) {
  x += dppf<0xB1>(x);
  x += dppf<0x4E>(x);
  x += dppf<0x124>(x);
  x += dppf<0x128>(x);
  return x;
}

#define QSCL 0.18033688011112042f  /* 0.125 * log2(e) */
#define LOG2E 1.4426950408889634f
#define SHIFT 16.0f                /* fixed softmax shift (log2 basis), folded into mask */

// ---------------- fused preprocessing: casts + weight transposes + segmask, one launch ----------------
__global__ __launch_bounds__(256) void pre_kernel(
    const float* __restrict__ h, const float* __restrict__ r, const float* __restrict__ wo,
    const float* __restrict__ w0, const float* __restrict__ w1,
    const float* __restrict__ w2, const float* __restrict__ w3,
    const unsigned char* __restrict__ seg, const float* __restrict__ mask,
    unsigned short* __restrict__ hb, unsigned short* __restrict__ rb,
    unsigned short* __restrict__ wo_b,
    unsigned short* __restrict__ o0, unsigned short* __restrict__ o1,
    unsigned short* __restrict__ o2, unsigned short* __restrict__ o3,
    unsigned int* __restrict__ segout) {
  __shared__ float t[32][33];
  const int bx = blockIdx.x;
  const int tid = threadIdx.x;
  if (bx < 7168) {
    int idx = bx * 256 + tid;
    const float* in;
    unsigned short* out;
    int o;
    if (idx < 524288) { in = h; out = hb; o = idx; }
    else if (idx < 1572864) { in = r; out = rb; o = idx - 524288; }
    else { in = wo; out = wo_b; o = idx - 1572864; }
    float4 v = ((const float4*)in)[o];
    us4 tt;
    tt[0] = f2bf(v.x); tt[1] = f2bf(v.y); tt[2] = f2bf(v.z); tt[3] = f2bf(v.w);
    *(us4*)&out[o * 4] = tt;
  } else if (bx < 11264) {
    int zz = bx - 7168;
    int z = zz >> 10, tt_ = zz & 1023;
    const float* in = z == 0 ? w0 : (z == 1 ? w1 : (z == 2 ? w2 : w3));
    unsigned short* out = z == 0 ? o0 : (z == 1 ? o1 : (z == 2 ? o2 : o3));
    int k0 = (tt_ >> 5) * 32;
    int n0 = (tt_ & 31) * 32;
    int rr = tid >> 5;
    int c = tid & 31;
#pragma unroll
    for (int s = 0; s < 4; ++s)
      t[rr + s * 8][c] = in[(k0 + rr + s * 8) * 1024 + n0 + c];
    __syncthreads();
#pragma unroll
    for (int s = 0; s < 4; ++s)
      out[(n0 + rr + s * 8) * 1024 + k0 + c] = f2bf(t[c][rr + s * 8]);
  } else {
    int ij = (bx - 11264) * 256 + tid;
    unsigned short sv = *(const unsigned short*)&seg[ij * 2];
    float2 mv = *(const float2*)&mask[(size_t)ij * 2];
    unsigned int q0 = ((unsigned int)f2bf(mv.x * -1.4426950408889634e30f - SHIFT) << 16) |
                      ((sv & 0xffu) ? 0x3f80u : 0u);
    unsigned int q1 = ((unsigned int)f2bf(mv.y * -1.4426950408889634e30f - SHIFT) << 16) |
                      ((sv >> 8) ? 0x3f80u : 0u);
    segout[ij] = q0;
    segout[1048576 + ij] = q1;
  }
}

// ---------------- all 4 projections (R7 structure) + fused dv epilogue + XCD swizzle ----------------
__global__ __launch_bounds__(512) void proj4_kernel(
    const unsigned short* __restrict__ hb, const unsigned short* __restrict__ rb,
    const unsigned short* __restrict__ wq_t, const unsigned short* __restrict__ wk_t,
    const unsigned short* __restrict__ wv_t, const unsigned short* __restrict__ wr_t,
    const float* __restrict__ rwb, const float* __restrict__ rrb, const float* __restrict__ rsb,
    const float* __restrict__ seg_embed,
    unsigned short* __restrict__ qwb, unsigned short* __restrict__ qrb,
    unsigned short* __restrict__ khb, unsigned short* __restrict__ vhb,
    unsigned short* __restrict__ krhb,
    float* __restrict__ dvb) {
  __shared__ unsigned short sA[2][128 * 64];
  __shared__ unsigned short sB[2][128 * 64];
  // XCD-aware swizzle (T1): each XCD gets 80 consecutive logical blocks
  // = 10 complete A-panels -> A-panel fetched once per XCD (was 8 XCDs).
  const int bx = (blockIdx.x & 7) * 80 + (blockIdx.x >> 3);
  int sel, rblk;
  const unsigned short* A;
  if (bx < 384) { sel = bx >> 7; rblk = bx & 127; A = hb; }
  else { sel = 3; rblk = bx - 384; A = rb; }
  const unsigned short* Bt = sel == 0 ? wq_t : (sel == 1 ? wk_t : (sel == 2 ? wv_t : wr_t));
  const int n0 = (rblk & 7) * 128, m0 = (rblk >> 3) * 128;
  const int tid = threadIdx.x, lane = tid & 63, w = tid >> 6;
  const int wm = w >> 1, wn = w & 1, g = lane >> 4, lc = lane & 15;

  f32x4 acc[2][4] = {};

  auto STAGE = [&](int buf, int kt) {
#pragma unroll
    for (int s = 0; s < 2; ++s) {
      int c = s * 512 + tid;
      int row = c >> 3;
      int ko = ((c & 7) ^ (row & 7)) * 8;
      int lbase = (s * 512 + w * 64) * 8;
      gload16(&A[(size_t)(m0 + row) * 1024 + kt + ko], &sA[buf][lbase]);
      gload16(&Bt[(size_t)(n0 + row) * 1024 + kt + ko], &sB[buf][lbase]);
    }
  };

  STAGE(0, 0);
  __syncthreads();

  for (int kt = 0; kt < 1024; kt += 64) {
    const int cur = (kt >> 6) & 1;
    if (kt < 960) STAGE(cur ^ 1, kt + 64);
    bf16x8 af[2][2], bfr[4][2];
#pragma unroll
    for (int ks = 0; ks < 2; ++ks) {
#pragma unroll
      for (int mi = 0; mi < 2; ++mi) {
        int ra = wm * 32 + mi * 16 + lc;
        af[mi][ks] = *(const bf16x8*)&sA[cur][ra * 64 + (((ks * 4 + g) ^ (ra & 7)) * 8)];
      }
#pragma unroll
      for (int ni = 0; ni < 4; ++ni) {
        int rb_ = wn * 64 + ni * 16 + lc;
        bfr[ni][ks] = *(const bf16x8*)&sB[cur][rb_ * 64 + (((ks * 4 + g) ^ (rb_ & 7)) * 8)];
      }
    }
#pragma unroll
    for (int ks = 0; ks < 2; ++ks)
#pragma unroll
      for (int mi = 0; mi < 2; ++mi)
#pragma unroll
        for (int ni = 0; ni < 4; ++ni)
          acc[mi][ni] = mfma16(af[mi][ks], bfr[ni][ks], acc[mi][ni]);
    __syncthreads();
  }

  if (sel == 0) {
    const int hn = (n0 >> 6) + wn;
    float sedv[4], bwv[4], brv[4], bsv[4];
#pragma unroll
    for (int ni = 0; ni < 4; ++ni) {
      int col = n0 + wn * 64 + ni * 16 + lc;
      sedv[ni] = seg_embed[1024 + hn * 64 + ni * 16 + lc] - seg_embed[hn * 64 + ni * 16 + lc];
      bwv[ni] = rwb[col];
      brv[ni] = rrb[col];
      bsv[ni] = rsb[col];
    }
#pragma unroll
    for (int mi = 0; mi < 2; ++mi) {
      int rowb = m0 + wm * 32 + mi * 16 + g * 4;
#pragma unroll
      for (int r = 0; r < 4; ++r) {
        float e = 0.f;
#pragma unroll
        for (int ni = 0; ni < 4; ++ni) {
          int col = n0 + wn * 64 + ni * 16 + lc;
          float v = acc[mi][ni][r];
          size_t idx = (size_t)(rowb + r) * 1024 + col;
          qwb[idx] = f2bf((v + bwv[ni]) * QSCL);
          qrb[idx] = f2bf((v + brv[ni]) * QSCL);
          e += (v + bsv[ni]) * 0.125f * sedv[ni];
        }
        e = rsum16(e);
        if (lc == 0) {
          int ib = rowb + r;
          int i = ib >> 1, b = ib & 1;
          dvb[(b * 16 + hn) * 1024 + i] = e * LOG2E;
        }
      }
    }
  } else {
#pragma unroll
    for (int ni = 0; ni < 4; ++ni) {
      int col = n0 + wn * 64 + ni * 16 + lc;
#pragma unroll
      for (int mi = 0; mi < 2; ++mi) {
        int rowb = m0 + wm * 32 + mi * 16 + g * 4;
#pragma unroll
        for (int r = 0; r < 4; ++r) {
          float v = acc[mi][ni][r];
          size_t idx = (size_t)(rowb + r) * 1024 + col;
          if (sel == 1) khb[idx] = f2bf(v);
          else if (sel == 2) vhb[idx] = f2bf(v);
          else krhb[idx] = f2bf(v);
        }
      }
    }
  }
}

// ---------------- out-projection: 64x128 tile, 8 waves, BK=64, 2-phase dbuf, swizzled + XCD swizzle ----------------
__global__ __launch_bounds__(512) void gemm64_out(const unsigned short* __restrict__ A,
                                                  const unsigned short* __restrict__ Bt,
                                                  float* __restrict__ C) {
  __shared__ unsigned short sA[2][64 * 64];
  __shared__ unsigned short sB[2][128 * 64];
  const int tid = threadIdx.x, lane = tid & 63, w = tid >> 6;
  const int wm = w >> 2, wn = w & 3, g = lane >> 4, lc = lane & 15;
  // XCD-aware swizzle: XCD c gets 4 complete m0-panels (A-panel read once per XCD)
  const int swz = (blockIdx.x & 7) * 32 + (blockIdx.x >> 3);
  const int m0 = (swz >> 3) * 64, n0 = (swz & 7) * 128;
  f32x4 acc[2][2] = {};

  auto STAGE = [&](int buf, int kt) {
    {
      int c = tid;
      int row = c >> 3;
      int ko = ((c & 7) ^ (row & 7)) * 8;
      gload16(&A[(size_t)(m0 + row) * 1024 + kt + ko], &sA[buf][w * 64 * 8]);
    }
#pragma unroll
    for (int s = 0; s < 2; ++s) {
      int c = s * 512 + tid;
      int row = c >> 3;
      int ko = ((c & 7) ^ (row & 7)) * 8;
      gload16(&Bt[(size_t)(n0 + row) * 1024 + kt + ko], &sB[buf][(s * 512 + w * 64) * 8]);
    }
  };

  STAGE(0, 0);
  __syncthreads();

  for (int kt = 0; kt < 1024; kt += 64) {
    const int cur = (kt >> 6) & 1;
    if (kt < 960) STAGE(cur ^ 1, kt + 64);
    bf16x8 af[2][2], bfr[2][2];
#pragma unroll
    for (int ks = 0; ks < 2; ++ks) {
#pragma unroll
      for (int mi = 0; mi < 2; ++mi) {
        int ra = wm * 32 + mi * 16 + lc;
        af[mi][ks] = *(const bf16x8*)&sA[cur][ra * 64 + (((ks * 4 + g) ^ (ra & 7)) * 8)];
      }
#pragma unroll
      for (int ni = 0; ni < 2; ++ni) {
        int rb_ = wn * 32 + ni * 16 + lc;
        bfr[ni][ks] = *(const bf16x8*)&sB[cur][rb_ * 64 + (((ks * 4 + g) ^ (rb_ & 7)) * 8)];
      }
    }
#pragma unroll
    for (int ks = 0; ks < 2; ++ks)
#pragma unroll
      for (int mi = 0; mi < 2; ++mi)
#pragma unroll
        for (int ni = 0; ni < 2; ++ni)
          acc[mi][ni] = mfma16(af[mi][ks], bfr[ni][ks], acc[mi][ni]);
    __syncthreads();
  }
#pragma unroll
  for (int ni = 0; ni < 2; ++ni) {
    int col = n0 + wn * 32 + ni * 16 + lc;
#pragma unroll
    for (int mi = 0; mi < 2; ++mi) {
      int rowb = m0 + wm * 32 + mi * 16 + g * 4;
#pragma unroll
      for (int r = 0; r < 4; ++r)
        C[(size_t)(rowb + r) * 1024 + col] = acc[mi][ni][r];
    }
  }
}

// ---------------- V transpose ----------------
__global__ __launch_bounds__(256) void transpose_v(const unsigned short* __restrict__ vh,
                                                   unsigned short* __restrict__ vT) {
  __shared__ unsigned short t[64][65];
  const int bn = blockIdx.y, j0 = blockIdx.x * 64;
  const int b = bn >> 4, n = bn & 15;
  const int r = threadIdx.x >> 4;
  const int c4 = (threadIdx.x & 15) * 4;
#pragma unroll
  for (int s = 0; s < 4; ++s) {
    int j = r + s * 16;
    us4 v = *(const us4*)&vh[((size_t)(j0 + j) * 2 + b) * 1024 + n * 64 + c4];
    t[j][c4 + 0] = v[0]; t[j][c4 + 1] = v[1]; t[j][c4 + 2] = v[2]; t[j][c4 + 3] = v[3];
  }
  __syncthreads();
#pragma unroll
  for (int s = 0; s < 4; ++s) {
    int d = r + s * 16;
    us4 v;
    v[0] = t[c4 + 0][d]; v[1] = t[c4 + 1][d]; v[2] = t[c4 + 2][d]; v[3] = t[c4 + 3][d];
    *(us4*)&vT[((size_t)bn * 64 + d) * 1024 + j0 + c4] = v;
  }
}

// ---------------- fused relative attention: R16 structure (fixed-shift softmax) ----------------
__global__ __launch_bounds__(512, 4) void attn_kernel(
    const unsigned short* __restrict__ qw, const unsigned short* __restrict__ qr,
    const unsigned short* __restrict__ kh, const unsigned short* __restrict__ krh,
    const unsigned short* __restrict__ vT,
    const float* __restrict__ dvb,
    const unsigned int* __restrict__ segmask,
    unsigned short* __restrict__ part, float* __restrict__ ml) {
  __shared__ unsigned short sK[64][64];    // chunk-XOR swizzled (key = row&7)
  __shared__ unsigned short sVT[64][64];   // chunk-XOR swizzled
  __shared__ unsigned short sKR[256][64];  // circular band, slot = jr & 255, chunk-XOR (key = jr&7)
  __shared__ unsigned short sP[8][16][72];

  const int tid = threadIdx.x, lane = tid & 63, w = tid >> 6;
  const int g = lane >> 4, lc = lane & 15;
  const int bn = blockIdx.x, b = bn >> 4, n = bn & 15;
  const int i0 = blockIdx.y * 128;
  const int js = blockIdx.z;
  const int S0 = 1024 + js * 512 - i0 - 127;

  bf16x8 fqw[2], fqr[2];
  const int qrow = i0 + w * 16 + lc;
#pragma unroll
  for (int ks = 0; ks < 2; ++ks) {
    size_t off = ((size_t)qrow * 2 + b) * 1024 + n * 64 + ks * 32 + g * 8;
    fqw[ks] = *(const bf16x8*)&qw[off];
    fqr[ks] = *(const bf16x8*)&qr[off];
  }
  float dv[4];
  unsigned int smoff[4];
#pragma unroll
  for (int r = 0; r < 4; ++r) {
    int i = i0 + w * 16 + g * 4 + r;
    dv[r] = dvb[bn * 1024 + i];
    smoff[r] = ((unsigned)b << 20) | ((unsigned)i << 10) | (unsigned)lc;
  }
  float lsum[4];
  f32x4 accO[4] = {};
#pragma unroll
  for (int r = 0; r < 4; ++r) lsum[r] = 0.f;

  const int srow = tid >> 3;
  const int pchk = tid & 7;
  const int skoK = ((pchk ^ (srow & 7))) * 8;
  const int skoR = ((pchk ^ ((S0 + srow) & 7))) * 8;
  const int ldst = pchk * 8;

#pragma unroll
  for (int pp = 0; pp < 3; ++pp) {
    int jr = S0 + pp * 64 + srow;
    *(uint4*)&sKR[jr & 255][ldst] =
        *(const uint4*)&krh[((size_t)jr * 2 + b) * 1024 + n * 64 + skoR];
  }
  int j0 = js * 512;
  uint4 rK = *(const uint4*)&kh[((size_t)(j0 + srow) * 2 + b) * 1024 + n * 64 + skoK];
  uint4 rV = *(const uint4*)&vT[((size_t)bn * 64 + srow) * 1024 + j0 + skoK];
  uint4 rR = *(const uint4*)&krh[((size_t)(S0 + 192 + srow) * 2 + b) * 1024 + n * 64 + skoR];

  for (int t = 0; t < 8; ++t) {
    j0 = (js * 8 + t) * 64;
    __syncthreads();
    *(uint4*)&sK[srow][ldst] = rK;
    *(uint4*)&sVT[srow][ldst] = rV;
    if (t < 7) {
      *(uint4*)&sKR[(S0 + 192 + t * 64 + srow) & 255][ldst] = rR;
      int j0n = j0 + 64;
      rK = *(const uint4*)&kh[((size_t)(j0n + srow) * 2 + b) * 1024 + n * 64 + skoK];
      rV = *(const uint4*)&vT[((size_t)bn * 64 + srow) * 1024 + j0n + skoK];
      if (t < 6) {
        int jr = S0 + 256 + t * 64 + srow;
        if (jr > 2047) jr = 2047;
        rR = *(const uint4*)&krh[((size_t)jr * 2 + b) * 1024 + n * 64 + skoR];
      }
    }
    unsigned int msv[4][4];
#pragma unroll
    for (int r = 0; r < 4; ++r)
#pragma unroll
      for (int nf = 0; nf < 4; ++nf)
        msv[r][nf] = segmask[smoff[r] + j0 + nf * 16];
    __syncthreads();

    const int base = S0 + t * 64 + (7 - w) * 16;
    const int krk = (S0 + lc) & 7;
    f32x4 bdk[5];
#pragma unroll
    for (int k = 0; k < 5; ++k) {
      f32x4 a = {0.f, 0.f, 0.f, 0.f};
#pragma unroll
      for (int ks = 0; ks < 2; ++ks) {
        bf16x8 fk = *(const bf16x8*)&sKR[(base + k * 16 + lc) & 255][(((ks * 4 + g) ^ krk)) * 8];
        a = mfma16(fqr[ks], fk, a);
      }
      bdk[k] = a;
    }
    float p[4][4];
#pragma unroll
    for (int r = 0; r < 4; ++r) {
      const int a_ = g * 4 + r;
      const int srcl = (lane & 48) | ((lc + 15 - a_) & 15);
      float s0 = __shfl(bdk[0][r], srcl);
      float s1 = __shfl(bdk[1][r], srcl);
      float s2 = __shfl(bdk[2][r], srcl);
      float s3 = __shfl(bdk[3][r], srcl);
      float s4 = __shfl(bdk[4][r], srcl);
      const bool lo = lc <= a_;
#pragma unroll
      for (int nf = 0; nf < 4; ++nf) {
        unsigned int u = msv[r][nf];
        float sgd = (u & 0xffffu) ? dv[r] : 0.f;
        float mkv = bf2f((unsigned short)(u >> 16));  // includes -SHIFT
        float bdv = lo ? (nf == 0 ? s0 : nf == 1 ? s1 : nf == 2 ? s2 : s3)
                       : (nf == 0 ? s1 : nf == 1 ? s2 : nf == 2 ? s3 : s4);
        p[r][nf] = sgd + mkv + bdv;
      }
    }
    f32x4 aa[4];
#pragma unroll
    for (int nf = 0; nf < 4; ++nf) {
      const int lk = lc & 7;
      f32x4 a = {0.f, 0.f, 0.f, 0.f};
#pragma unroll
      for (int ks = 0; ks < 2; ++ks) {
        bf16x8 fk = *(const bf16x8*)&sK[nf * 16 + lc][(((ks * 4 + g) ^ lk)) * 8];
        a = mfma16(fqw[ks], fk, a);
      }
      aa[nf] = a;
    }
#pragma unroll
    for (int r = 0; r < 4; ++r)
#pragma unroll
      for (int nf = 0; nf < 4; ++nf) p[r][nf] += aa[nf][r];

#pragma unroll
    for (int r = 0; r < 4; ++r) {
      float se = 0.f;
#pragma unroll
      for (int nf = 0; nf < 4; ++nf) {
        float e = fexp2(p[r][nf]);
        p[r][nf] = e;
        se += e;
      }
      se = rsum16(se);
      lsum[r] += se;
#pragma unroll
      for (int nf = 0; nf < 4; ++nf)
        sP[w][g * 4 + r][nf * 16 + lc] = f2bf(p[r][nf]);
    }
#pragma unroll
    for (int ks = 0; ks < 2; ++ks) {
      bf16x8 fp = *(const bf16x8*)&sP[w][lc][ks * 32 + g * 8];
#pragma unroll
      for (int df = 0; df < 4; ++df) {
        const int vk = lc & 7;
        bf16x8 fv = *(const bf16x8*)&sVT[df * 16 + lc][(((ks * 4 + g) ^ vk)) * 8];
        accO[df] = mfma16(fp, fv, accO[df]);
      }
    }
  }
#pragma unroll
  for (int r = 0; r < 4; ++r) {
    int i = i0 + w * 16 + g * 4 + r;
    size_t pb = ((size_t)(js * 32 + bn) * 1024 + i) * 64;
#pragma unroll
    for (int df = 0; df < 4; ++df) part[pb + df * 16 + lc] = f2bf(accO[df][r]);
    if (lc == 0) ml[((size_t)js * 32 + bn) * 1024 + i] = lsum[r];
  }
}

// ---------------- combine the two j-splits (fixed-shift: plain sum) ----------------
__global__ __launch_bounds__(256) void combine_kernel(const unsigned short* __restrict__ part,
                                                      const float* __restrict__ ml,
                                                      unsigned short* __restrict__ av) {
  int gw = blockIdx.x * 4 + (threadIdx.x >> 6);
  int lane = threadIdx.x & 63;
  int bn = gw >> 10, i = gw & 1023;
  int b = bn >> 4, n = bn & 15;
  float l0 = ml[(size_t)bn * 1024 + i];
  float l1 = ml[((size_t)32 + bn) * 1024 + i];
  float inv = 1.f / (l0 + l1);
  float o = bf2f(part[((size_t)bn * 1024 + i) * 64 + lane]) +
            bf2f(part[(((size_t)32 + bn) * 1024 + i) * 64 + lane]);
  av[((size_t)i * 2 + b) * 1024 + n * 64 + lane] = f2bf(o * inv);
}

// ---------------- residual + LayerNorm ----------------
__global__ __launch_bounds__(256) void ln_kernel(const float* __restrict__ gout,
                                                 const float* __restrict__ h,
                                                 const float* __restrict__ gamma,
                                                 const float* __restrict__ beta,
                                                 float* __restrict__ out) {
  __shared__ float red[8];
  const int row = blockIdx.x;
  const int tid = threadIdx.x;
  float x[4];
  float s = 0.f;
#pragma unroll
  for (int q = 0; q < 4; ++q) {
    int d = tid + q * 256;
    x[q] = gout[(size_t)row * 1024 + d] + h[(size_t)row * 1024 + d];
    s += x[q];
  }
#pragma unroll
  for (int m = 1; m < 64; m <<= 1) s += __shfl_xor(s, m);
  if ((tid & 63) == 0) red[tid >> 6] = s;
  __syncthreads();
  s = red[0] + red[1] + red[2] + red[3];
  float mu = s * (1.f / 1024.f);
  float v = 0.f;
#pragma unroll
  for (int q = 0; q < 4; ++q) {
    float dd = x[q] - mu;
    v += dd * dd;
  }
#pragma unroll
  for (int m = 1; m < 64; m <<= 1) v += __shfl_xor(v, m);
  if ((tid & 63) == 0) red[4 + (tid >> 6)] = v;
  __syncthreads();
  v = red[4] + red[5] + red[6] + red[7];
  float rstd = rsqrtf(v * (1.f / 1024.f) + 1e-12f);
#pragma unroll
  for (int q = 0; q < 4; ++q) {
    int d = tid + q * 256;
    out[(size_t)row * 1024 + d] = (x[q] - mu) * rstd * gamma[d] + beta[d];
  }
}

extern "C" void kernel_launch(void* const* d_in, const int* in_sizes, int n_in,
                              void* d_out, int out_size, void* d_ws, size_t ws_size,
                              hipStream_t stream) {
  const float* h = (const float*)d_in[0];
  const float* r = (const float*)d_in[1];
  const unsigned char* seg = (const unsigned char*)d_in[2];
  const float* mask = (const float*)d_in[3];
  const float* wq = (const float*)d_in[4];
  const float* wk = (const float*)d_in[5];
  const float* wv = (const float*)d_in[6];
  const float* wr = (const float*)d_in[7];
  const float* wo = (const float*)d_in[8];
  const float* rwb = (const float*)d_in[9];
  const float* rrb = (const float*)d_in[10];
  const float* rsb = (const float*)d_in[11];
  const float* seg_embed = (const float*)d_in[12];
  const float* gamma = (const float*)d_in[13];
  const float* beta = (const float*)d_in[14];
  float* out = (float*)d_out;

  char* ws = (char*)d_ws;
  size_t off = 0;
  auto alloc = [&](size_t bytes) {
    size_t cur = off;
    off = (off + bytes + 255) & ~(size_t)255;
    return cur;
  };
  unsigned short* hb = (unsigned short*)(ws + alloc(2048 * 1024 * 2));
  unsigned short* rb = (unsigned short*)(ws + alloc(4096 * 1024 * 2));
  unsigned short* wq_t = (unsigned short*)(ws + alloc(1024 * 1024 * 2));
  unsigned short* wk_t = (unsigned short*)(ws + alloc(1024 * 1024 * 2));
  unsigned short* wv_t = (unsigned short*)(ws + alloc(1024 * 1024 * 2));
  unsigned short* wr_t = (unsigned short*)(ws + alloc(1024 * 1024 * 2));
  unsigned short* wo_b = (unsigned short*)(ws + alloc(1024 * 1024 * 2));
  unsigned short* qwb = (unsigned short*)(ws + alloc(2048 * 1024 * 2));
  unsigned short* qrb = (unsigned short*)(ws + alloc(2048 * 1024 * 2));
  unsigned short* khb = (unsigned short*)(ws + alloc(2048 * 1024 * 2));
  unsigned short* vhb = (unsigned short*)(ws + alloc(2048 * 1024 * 2));
  unsigned short* krhb = (unsigned short*)(ws + alloc(4096 * 1024 * 2));
  unsigned short* vTb = (unsigned short*)(ws + alloc(2048 * 1024 * 2));
  float* dvb = (float*)(ws + alloc(2048 * 16 * 4));
  unsigned int* segmask = (unsigned int*)(ws + alloc(2 * 1024 * 1024 * 4));
  unsigned short* avb = (unsigned short*)(ws + alloc(2048 * 1024 * 2));
  float* gout = (float*)(ws + alloc(2048 * 1024 * 4));
  unsigned short* part = (unsigned short*)(ws + alloc((size_t)2 * 32 * 1024 * 64 * 2));
  float* mlb = (float*)(ws + alloc((size_t)2 * 32 * 1024 * 4));
  (void)ws_size; (void)in_sizes; (void)n_in; (void)out_size;

  pre_kernel<<<15360, 256, 0, stream>>>(h, r, wo, wq, wk, wv, wr, seg, mask,
                                        hb, rb, wo_b, wq_t, wk_t, wv_t, wr_t, segmask);

  proj4_kernel<<<640, 512, 0, stream>>>(hb, rb, wq_t, wk_t, wv_t, wr_t, rwb, rrb, rsb,
                                        seg_embed, qwb, qrb, khb, vhb, krhb, dvb);

  transpose_v<<<dim3(16, 32), 256, 0, stream>>>(vhb, vTb);

  attn_kernel<<<dim3(32, 8, 2), 512, 0, stream>>>(qwb, qrb, khb, krhb, vTb,
                                                  dvb, segmask, part, mlb);
  combine_kernel<<<8192, 256, 0, stream>>>(part, mlb, avb);

  gemm64_out<<<256, 512, 0, stream>>>(avb, wo_b, gout);
  ln_kernel<<<2048, 256, 0, stream>>>(gout, h, gamma, beta, out);
}

// Round 18
// 119.951 us; speedup vs baseline: 1.4351x; 1.0048x over previous
//
#include <hip/hip_runtime.h>

typedef __bf16 bf16x8 __attribute__((ext_vector_type(8)));
typedef float f32x4 __attribute__((ext_vector_type(4)));
typedef unsigned short us4 __attribute__((ext_vector_type(4)));

__device__ __forceinline__ unsigned short f2bf(float f) {
  unsigned int u = __builtin_bit_cast(unsigned int, f);
  u += 0x7fffu + ((u >> 16) & 1u);
  return (unsigned short)(u >> 16);
}
__device__ __forceinline__ float bf2f(unsigned short s) {
  unsigned int u = ((unsigned int)s) << 16;
  return __builtin_bit_cast(float, u);
}
__device__ __forceinline__ f32x4 mfma16(bf16x8 a, bf16x8 b, f32x4 c) {
  return __builtin_amdgcn_mfma_f32_16x16x32_bf16(a, b, c, 0, 0, 0);
}
__device__ __forceinline__ void gload16(const void* g, void* l) {
  __builtin_amdgcn_global_load_lds(
      (const __attribute__((address_space(1))) unsigned int*)g,
      (__attribute__((address_space(3))) unsigned int*)l, 16, 0, 0);
}
__device__ __forceinline__ float fexp2(float x) {
  float r;
  asm("v_exp_f32 %0, %1" : "=v"(r) : "v"(x));
  return r;
}
template <int CTRL>
__device__ __forceinline__ float dppf(float x) {
  return __builtin_bit_cast(
      float, __builtin_amdgcn_mov_dpp(__builtin_bit_cast(int, x), CTRL, 0xf, 0xf, true));
}
__device__ __forceinline__ float rsum16(float x) {
  x += dppf<0xB1>(x);
  x += dppf<0x4E>(x);
  x += dppf<0x124>(x);
  x += dppf<0x128>(x);
  return x;
}

#define QSCL 0.18033688011112042f  /* 0.125 * log2(e) */
#define LOG2E 1.4426950408889634f
#define SHIFT 16.0f                /* fixed softmax shift (log2 basis), folded into mask */

// ---------------- fused preprocessing: casts + weight transposes + segmask, one launch ----------------
__global__ __launch_bounds__(256) void pre_kernel(
    const float* __restrict__ h, const float* __restrict__ r, const float* __restrict__ wo,
    const float* __restrict__ w0, const float* __restrict__ w1,
    const float* __restrict__ w2, const float* __restrict__ w3,
    const unsigned char* __restrict__ seg, const float* __restrict__ mask,
    unsigned short* __restrict__ hb, unsigned short* __restrict__ rb,
    unsigned short* __restrict__ wo_b,
    unsigned short* __restrict__ o0, unsigned short* __restrict__ o1,
    unsigned short* __restrict__ o2, unsigned short* __restrict__ o3,
    unsigned int* __restrict__ segout) {
  __shared__ float t[32][33];
  const int bx = blockIdx.x;
  const int tid = threadIdx.x;
  if (bx < 7168) {
    int idx = bx * 256 + tid;
    const float* in;
    unsigned short* out;
    int o;
    if (idx < 524288) { in = h; out = hb; o = idx; }
    else if (idx < 1572864) { in = r; out = rb; o = idx - 524288; }
    else { in = wo; out = wo_b; o = idx - 1572864; }
    float4 v = ((const float4*)in)[o];
    us4 tt;
    tt[0] = f2bf(v.x); tt[1] = f2bf(v.y); tt[2] = f2bf(v.z); tt[3] = f2bf(v.w);
    *(us4*)&out[o * 4] = tt;
  } else if (bx < 11264) {
    int zz = bx - 7168;
    int z = zz >> 10, tt_ = zz & 1023;
    const float* in = z == 0 ? w0 : (z == 1 ? w1 : (z == 2 ? w2 : w3));
    unsigned short* out = z == 0 ? o0 : (z == 1 ? o1 : (z == 2 ? o2 : o3));
    int k0 = (tt_ >> 5) * 32;
    int n0 = (tt_ & 31) * 32;
    int rr = tid >> 5;
    int c = tid & 31;
#pragma unroll
    for (int s = 0; s < 4; ++s)
      t[rr + s * 8][c] = in[(k0 + rr + s * 8) * 1024 + n0 + c];
    __syncthreads();
#pragma unroll
    for (int s = 0; s < 4; ++s)
      out[(n0 + rr + s * 8) * 1024 + k0 + c] = f2bf(t[c][rr + s * 8]);
  } else {
    int ij = (bx - 11264) * 256 + tid;
    unsigned short sv = *(const unsigned short*)&seg[ij * 2];
    float2 mv = *(const float2*)&mask[(size_t)ij * 2];
    unsigned int q0 = ((unsigned int)f2bf(mv.x * -1.4426950408889634e30f - SHIFT) << 16) |
                      ((sv & 0xffu) ? 0x3f80u : 0u);
    unsigned int q1 = ((unsigned int)f2bf(mv.y * -1.4426950408889634e30f - SHIFT) << 16) |
                      ((sv >> 8) ? 0x3f80u : 0u);
    segout[ij] = q0;
    segout[1048576 + ij] = q1;
  }
}

// ---------------- all 4 projections (R7 structure) + fused dv epilogue + XCD swizzle ----------------
__global__ __launch_bounds__(512) void proj4_kernel(
    const unsigned short* __restrict__ hb, const unsigned short* __restrict__ rb,
    const unsigned short* __restrict__ wq_t, const unsigned short* __restrict__ wk_t,
    const unsigned short* __restrict__ wv_t, const unsigned short* __restrict__ wr_t,
    const float* __restrict__ rwb, const float* __restrict__ rrb, const float* __restrict__ rsb,
    const float* __restrict__ seg_embed,
    unsigned short* __restrict__ qwb, unsigned short* __restrict__ qrb,
    unsigned short* __restrict__ khb, unsigned short* __restrict__ vhb,
    unsigned short* __restrict__ krhb,
    float* __restrict__ dvb) {
  __shared__ unsigned short sA[2][128 * 64];
  __shared__ unsigned short sB[2][128 * 64];
  const int bx = (blockIdx.x & 7) * 80 + (blockIdx.x >> 3);
  int sel, rblk;
  const unsigned short* A;
  if (bx < 384) { sel = bx >> 7; rblk = bx & 127; A = hb; }
  else { sel = 3; rblk = bx - 384; A = rb; }
  const unsigned short* Bt = sel == 0 ? wq_t : (sel == 1 ? wk_t : (sel == 2 ? wv_t : wr_t));
  const int n0 = (rblk & 7) * 128, m0 = (rblk >> 3) * 128;
  const int tid = threadIdx.x, lane = tid & 63, w = tid >> 6;
  const int wm = w >> 1, wn = w & 1, g = lane >> 4, lc = lane & 15;

  f32x4 acc[2][4] = {};

  auto STAGE = [&](int buf, int kt) {
#pragma unroll
    for (int s = 0; s < 2; ++s) {
      int c = s * 512 + tid;
      int row = c >> 3;
      int ko = ((c & 7) ^ (row & 7)) * 8;
      int lbase = (s * 512 + w * 64) * 8;
      gload16(&A[(size_t)(m0 + row) * 1024 + kt + ko], &sA[buf][lbase]);
      gload16(&Bt[(size_t)(n0 + row) * 1024 + kt + ko], &sB[buf][lbase]);
    }
  };

  STAGE(0, 0);
  __syncthreads();

  for (int kt = 0; kt < 1024; kt += 64) {
    const int cur = (kt >> 6) & 1;
    if (kt < 960) STAGE(cur ^ 1, kt + 64);
    bf16x8 af[2][2], bfr[4][2];
#pragma unroll
    for (int ks = 0; ks < 2; ++ks) {
#pragma unroll
      for (int mi = 0; mi < 2; ++mi) {
        int ra = wm * 32 + mi * 16 + lc;
        af[mi][ks] = *(const bf16x8*)&sA[cur][ra * 64 + (((ks * 4 + g) ^ (ra & 7)) * 8)];
      }
#pragma unroll
      for (int ni = 0; ni < 4; ++ni) {
        int rb_ = wn * 64 + ni * 16 + lc;
        bfr[ni][ks] = *(const bf16x8*)&sB[cur][rb_ * 64 + (((ks * 4 + g) ^ (rb_ & 7)) * 8)];
      }
    }
#pragma unroll
    for (int ks = 0; ks < 2; ++ks)
#pragma unroll
      for (int mi = 0; mi < 2; ++mi)
#pragma unroll
        for (int ni = 0; ni < 4; ++ni)
          acc[mi][ni] = mfma16(af[mi][ks], bfr[ni][ks], acc[mi][ni]);
    __syncthreads();
  }

  if (sel == 0) {
    const int hn = (n0 >> 6) + wn;
    float sedv[4], bwv[4], brv[4], bsv[4];
#pragma unroll
    for (int ni = 0; ni < 4; ++ni) {
      int col = n0 + wn * 64 + ni * 16 + lc;
      sedv[ni] = seg_embed[1024 + hn * 64 + ni * 16 + lc] - seg_embed[hn * 64 + ni * 16 + lc];
      bwv[ni] = rwb[col];
      brv[ni] = rrb[col];
      bsv[ni] = rsb[col];
    }
#pragma unroll
    for (int mi = 0; mi < 2; ++mi) {
      int rowb = m0 + wm * 32 + mi * 16 + g * 4;
#pragma unroll
      for (int r = 0; r < 4; ++r) {
        float e = 0.f;
#pragma unroll
        for (int ni = 0; ni < 4; ++ni) {
          int col = n0 + wn * 64 + ni * 16 + lc;
          float v = acc[mi][ni][r];
          size_t idx = (size_t)(rowb + r) * 1024 + col;
          qwb[idx] = f2bf((v + bwv[ni]) * QSCL);
          qrb[idx] = f2bf((v + brv[ni]) * QSCL);
          e += (v + bsv[ni]) * 0.125f * sedv[ni];
        }
        e = rsum16(e);
        if (lc == 0) {
          int ib = rowb + r;
          int i = ib >> 1, b = ib & 1;
          dvb[(b * 16 + hn) * 1024 + i] = e * LOG2E;
        }
      }
    }
  } else {
#pragma unroll
    for (int ni = 0; ni < 4; ++ni) {
      int col = n0 + wn * 64 + ni * 16 + lc;
#pragma unroll
      for (int mi = 0; mi < 2; ++mi) {
        int rowb = m0 + wm * 32 + mi * 16 + g * 4;
#pragma unroll
        for (int r = 0; r < 4; ++r) {
          float v = acc[mi][ni][r];
          size_t idx = (size_t)(rowb + r) * 1024 + col;
          if (sel == 1) khb[idx] = f2bf(v);
          else if (sel == 2) vhb[idx] = f2bf(v);
          else krhb[idx] = f2bf(v);
        }
      }
    }
  }
}

// ---------------- out-projection: bf16 output (gout) ----------------
__global__ __launch_bounds__(512) void gemm64_out(const unsigned short* __restrict__ A,
                                                  const unsigned short* __restrict__ Bt,
                                                  unsigned short* __restrict__ C) {
  __shared__ unsigned short sA[2][64 * 64];
  __shared__ unsigned short sB[2][128 * 64];
  const int tid = threadIdx.x, lane = tid & 63, w = tid >> 6;
  const int wm = w >> 2, wn = w & 3, g = lane >> 4, lc = lane & 15;
  const int swz = (blockIdx.x & 7) * 32 + (blockIdx.x >> 3);
  const int m0 = (swz >> 3) * 64, n0 = (swz & 7) * 128;
  f32x4 acc[2][2] = {};

  auto STAGE = [&](int buf, int kt) {
    {
      int c = tid;
      int row = c >> 3;
      int ko = ((c & 7) ^ (row & 7)) * 8;
      gload16(&A[(size_t)(m0 + row) * 1024 + kt + ko], &sA[buf][w * 64 * 8]);
    }
#pragma unroll
    for (int s = 0; s < 2; ++s) {
      int c = s * 512 + tid;
      int row = c >> 3;
      int ko = ((c & 7) ^ (row & 7)) * 8;
      gload16(&Bt[(size_t)(n0 + row) * 1024 + kt + ko], &sB[buf][(s * 512 + w * 64) * 8]);
    }
  };

  STAGE(0, 0);
  __syncthreads();

  for (int kt = 0; kt < 1024; kt += 64) {
    const int cur = (kt >> 6) & 1;
    if (kt < 960) STAGE(cur ^ 1, kt + 64);
    bf16x8 af[2][2], bfr[2][2];
#pragma unroll
    for (int ks = 0; ks < 2; ++ks) {
#pragma unroll
      for (int mi = 0; mi < 2; ++mi) {
        int ra = wm * 32 + mi * 16 + lc;
        af[mi][ks] = *(const bf16x8*)&sA[cur][ra * 64 + (((ks * 4 + g) ^ (ra & 7)) * 8)];
      }
#pragma unroll
      for (int ni = 0; ni < 2; ++ni) {
        int rb_ = wn * 32 + ni * 16 + lc;
        bfr[ni][ks] = *(const bf16x8*)&sB[cur][rb_ * 64 + (((ks * 4 + g) ^ (rb_ & 7)) * 8)];
      }
    }
#pragma unroll
    for (int ks = 0; ks < 2; ++ks)
#pragma unroll
      for (int mi = 0; mi < 2; ++mi)
#pragma unroll
        for (int ni = 0; ni < 2; ++ni)
          acc[mi][ni] = mfma16(af[mi][ks], bfr[ni][ks], acc[mi][ni]);
    __syncthreads();
  }
#pragma unroll
  for (int ni = 0; ni < 2; ++ni) {
    int col = n0 + wn * 32 + ni * 16 + lc;
#pragma unroll
    for (int mi = 0; mi < 2; ++mi) {
      int rowb = m0 + wm * 32 + mi * 16 + g * 4;
#pragma unroll
      for (int r = 0; r < 4; ++r)
        C[(size_t)(rowb + r) * 1024 + col] = f2bf(acc[mi][ni][r]);
    }
  }
}

// ---------------- V transpose ----------------
__global__ __launch_bounds__(256) void transpose_v(const unsigned short* __restrict__ vh,
                                                   unsigned short* __restrict__ vT) {
  __shared__ unsigned short t[64][65];
  const int bn = blockIdx.y, j0 = blockIdx.x * 64;
  const int b = bn >> 4, n = bn & 15;
  const int r = threadIdx.x >> 4;
  const int c4 = (threadIdx.x & 15) * 4;
#pragma unroll
  for (int s = 0; s < 4; ++s) {
    int j = r + s * 16;
    us4 v = *(const us4*)&vh[((size_t)(j0 + j) * 2 + b) * 1024 + n * 64 + c4];
    t[j][c4 + 0] = v[0]; t[j][c4 + 1] = v[1]; t[j][c4 + 2] = v[2]; t[j][c4 + 3] = v[3];
  }
  __syncthreads();
#pragma unroll
  for (int s = 0; s < 4; ++s) {
    int d = r + s * 16;
    us4 v;
    v[0] = t[c4 + 0][d]; v[1] = t[c4 + 1][d]; v[2] = t[c4 + 2][d]; v[3] = t[c4 + 3][d];
    *(us4*)&vT[((size_t)bn * 64 + d) * 1024 + j0 + c4] = v;
  }
}

// ---------------- fused relative attention: R17 structure (fixed-shift softmax) ----------------
__global__ __launch_bounds__(512, 4) void attn_kernel(
    const unsigned short* __restrict__ qw, const unsigned short* __restrict__ qr,
    const unsigned short* __restrict__ kh, const unsigned short* __restrict__ krh,
    const unsigned short* __restrict__ vT,
    const float* __restrict__ dvb,
    const unsigned int* __restrict__ segmask,
    unsigned short* __restrict__ part, float* __restrict__ ml) {
  __shared__ unsigned short sK[64][64];
  __shared__ unsigned short sVT[64][64];
  __shared__ unsigned short sKR[256][64];
  __shared__ unsigned short sP[8][16][72];

  const int tid = threadIdx.x, lane = tid & 63, w = tid >> 6;
  const int g = lane >> 4, lc = lane & 15;
  const int bn = blockIdx.x, b = bn >> 4, n = bn & 15;
  const int i0 = blockIdx.y * 128;
  const int js = blockIdx.z;
  const int S0 = 1024 + js * 512 - i0 - 127;

  bf16x8 fqw[2], fqr[2];
  const int qrow = i0 + w * 16 + lc;
#pragma unroll
  for (int ks = 0; ks < 2; ++ks) {
    size_t off = ((size_t)qrow * 2 + b) * 1024 + n * 64 + ks * 32 + g * 8;
    fqw[ks] = *(const bf16x8*)&qw[off];
    fqr[ks] = *(const bf16x8*)&qr[off];
  }
  float dv[4];
  unsigned int smoff[4];
#pragma unroll
  for (int r = 0; r < 4; ++r) {
    int i = i0 + w * 16 + g * 4 + r;
    dv[r] = dvb[bn * 1024 + i];
    smoff[r] = ((unsigned)b << 20) | ((unsigned)i << 10) | (unsigned)lc;
  }
  float lsum[4];
  f32x4 accO[4] = {};
#pragma unroll
  for (int r = 0; r < 4; ++r) lsum[r] = 0.f;

  const int srow = tid >> 3;
  const int pchk = tid & 7;
  const int skoK = ((pchk ^ (srow & 7))) * 8;
  const int skoR = ((pchk ^ ((S0 + srow) & 7))) * 8;
  const int ldst = pchk * 8;

#pragma unroll
  for (int pp = 0; pp < 3; ++pp) {
    int jr = S0 + pp * 64 + srow;
    *(uint4*)&sKR[jr & 255][ldst] =
        *(const uint4*)&krh[((size_t)jr * 2 + b) * 1024 + n * 64 + skoR];
  }
  int j0 = js * 512;
  uint4 rK = *(const uint4*)&kh[((size_t)(j0 + srow) * 2 + b) * 1024 + n * 64 + skoK];
  uint4 rV = *(const uint4*)&vT[((size_t)bn * 64 + srow) * 1024 + j0 + skoK];
  uint4 rR = *(const uint4*)&krh[((size_t)(S0 + 192 + srow) * 2 + b) * 1024 + n * 64 + skoR];

  for (int t = 0; t < 8; ++t) {
    j0 = (js * 8 + t) * 64;
    __syncthreads();
    *(uint4*)&sK[srow][ldst] = rK;
    *(uint4*)&sVT[srow][ldst] = rV;
    if (t < 7) {
      *(uint4*)&sKR[(S0 + 192 + t * 64 + srow) & 255][ldst] = rR;
      int j0n = j0 + 64;
      rK = *(const uint4*)&kh[((size_t)(j0n + srow) * 2 + b) * 1024 + n * 64 + skoK];
      rV = *(const uint4*)&vT[((size_t)bn * 64 + srow) * 1024 + j0n + skoK];
      if (t < 6) {
        int jr = S0 + 256 + t * 64 + srow;
        if (jr > 2047) jr = 2047;
        rR = *(const uint4*)&krh[((size_t)jr * 2 + b) * 1024 + n * 64 + skoR];
      }
    }
    unsigned int msv[4][4];
#pragma unroll
    for (int r = 0; r < 4; ++r)
#pragma unroll
      for (int nf = 0; nf < 4; ++nf)
        msv[r][nf] = segmask[smoff[r] + j0 + nf * 16];
    __syncthreads();

    const int base = S0 + t * 64 + (7 - w) * 16;
    const int krk = (S0 + lc) & 7;
    f32x4 bdk[5];
#pragma unroll
    for (int k = 0; k < 5; ++k) {
      f32x4 a = {0.f, 0.f, 0.f, 0.f};
#pragma unroll
      for (int ks = 0; ks < 2; ++ks) {
        bf16x8 fk = *(const bf16x8*)&sKR[(base + k * 16 + lc) & 255][(((ks * 4 + g) ^ krk)) * 8];
        a = mfma16(fqr[ks], fk, a);
      }
      bdk[k] = a;
    }
    float p[4][4];
#pragma unroll
    for (int r = 0; r < 4; ++r) {
      const int a_ = g * 4 + r;
      const int srcl = (lane & 48) | ((lc + 15 - a_) & 15);
      float s0 = __shfl(bdk[0][r], srcl);
      float s1 = __shfl(bdk[1][r], srcl);
      float s2 = __shfl(bdk[2][r], srcl);
      float s3 = __shfl(bdk[3][r], srcl);
      float s4 = __shfl(bdk[4][r], srcl);
      const bool lo = lc <= a_;
#pragma unroll
      for (int nf = 0; nf < 4; ++nf) {
        unsigned int u = msv[r][nf];
        float sgd = (u & 0xffffu) ? dv[r] : 0.f;
        float mkv = bf2f((unsigned short)(u >> 16));
        float bdv = lo ? (nf == 0 ? s0 : nf == 1 ? s1 : nf == 2 ? s2 : s3)
                       : (nf == 0 ? s1 : nf == 1 ? s2 : nf == 2 ? s3 : s4);
        p[r][nf] = sgd + mkv + bdv;
      }
    }
    f32x4 aa[4];
#pragma unroll
    for (int nf = 0; nf < 4; ++nf) {
      const int lk = lc & 7;
      f32x4 a = {0.f, 0.f, 0.f, 0.f};
#pragma unroll
      for (int ks = 0; ks < 2; ++ks) {
        bf16x8 fk = *(const bf16x8*)&sK[nf * 16 + lc][(((ks * 4 + g) ^ lk)) * 8];
        a = mfma16(fqw[ks], fk, a);
      }
      aa[nf] = a;
    }
#pragma unroll
    for (int r = 0; r < 4; ++r)
#pragma unroll
      for (int nf = 0; nf < 4; ++nf) p[r][nf] += aa[nf][r];

#pragma unroll
    for (int r = 0; r < 4; ++r) {
      float se = 0.f;
#pragma unroll
      for (int nf = 0; nf < 4; ++nf) {
        float e = fexp2(p[r][nf]);
        p[r][nf] = e;
        se += e;
      }
      se = rsum16(se);
      lsum[r] += se;
#pragma unroll
      for (int nf = 0; nf < 4; ++nf)
        sP[w][g * 4 + r][nf * 16 + lc] = f2bf(p[r][nf]);
    }
#pragma unroll
    for (int ks = 0; ks < 2; ++ks) {
      bf16x8 fp = *(const bf16x8*)&sP[w][lc][ks * 32 + g * 8];
#pragma unroll
      for (int df = 0; df < 4; ++df) {
        const int vk = lc & 7;
        bf16x8 fv = *(const bf16x8*)&sVT[df * 16 + lc][(((ks * 4 + g) ^ vk)) * 8];
        accO[df] = mfma16(fp, fv, accO[df]);
      }
    }
  }
#pragma unroll
  for (int r = 0; r < 4; ++r) {
    int i = i0 + w * 16 + g * 4 + r;
    size_t pb = ((size_t)(js * 32 + bn) * 1024 + i) * 64;
#pragma unroll
    for (int df = 0; df < 4; ++df) part[pb + df * 16 + lc] = f2bf(accO[df][r]);
    if (lc == 0) ml[((size_t)js * 32 + bn) * 1024 + i] = lsum[r];
  }
}

// ---------------- combine the two j-splits (fixed-shift: plain sum) ----------------
__global__ __launch_bounds__(256) void combine_kernel(const unsigned short* __restrict__ part,
                                                      const float* __restrict__ ml,
                                                      unsigned short* __restrict__ av) {
  int gw = blockIdx.x * 4 + (threadIdx.x >> 6);
  int lane = threadIdx.x & 63;
  int bn = gw >> 10, i = gw & 1023;
  int b = bn >> 4, n = bn & 15;
  float l0 = ml[(size_t)bn * 1024 + i];
  float l1 = ml[((size_t)32 + bn) * 1024 + i];
  float inv = 1.f / (l0 + l1);
  float o = bf2f(part[((size_t)bn * 1024 + i) * 64 + lane]) +
            bf2f(part[(((size_t)32 + bn) * 1024 + i) * 64 + lane]);
  av[((size_t)i * 2 + b) * 1024 + n * 64 + lane] = f2bf(o * inv);
}

// ---------------- residual + LayerNorm (bf16 gout) ----------------
__global__ __launch_bounds__(256) void ln_kernel(const unsigned short* __restrict__ gout,
                                                 const float* __restrict__ h,
                                                 const float* __restrict__ gamma,
                                                 const float* __restrict__ beta,
                                                 float* __restrict__ out) {
  __shared__ float red[8];
  const int row = blockIdx.x;
  const int tid = threadIdx.x;
  float x[4];
  float s = 0.f;
#pragma unroll
  for (int q = 0; q < 4; ++q) {
    int d = tid + q * 256;
    x[q] = bf2f(gout[(size_t)row * 1024 + d]) + h[(size_t)row * 1024 + d];
    s += x[q];
  }
#pragma unroll
  for (int m = 1; m < 64; m <<= 1) s += __shfl_xor(s, m);
  if ((tid & 63) == 0) red[tid >> 6] = s;
  __syncthreads();
  s = red[0] + red[1] + red[2] + red[3];
  float mu = s * (1.f / 1024.f);
  float v = 0.f;
#pragma unroll
  for (int q = 0; q < 4; ++q) {
    float dd = x[q] - mu;
    v += dd * dd;
  }
#pragma unroll
  for (int m = 1; m < 64; m <<= 1) v += __shfl_xor(v, m);
  if ((tid & 63) == 0) red[4 + (tid >> 6)] = v;
  __syncthreads();
  v = red[4] + red[5] + red[6] + red[7];
  float rstd = rsqrtf(v * (1.f / 1024.f) + 1e-12f);
#pragma unroll
  for (int q = 0; q < 4; ++q) {
    int d = tid + q * 256;
    out[(size_t)row * 1024 + d] = (x[q] - mu) * rstd * gamma[d] + beta[d];
  }
}

extern "C" void kernel_launch(void* const* d_in, const int* in_sizes, int n_in,
                              void* d_out, int out_size, void* d_ws, size_t ws_size,
                              hipStream_t stream) {
  const float* h = (const float*)d_in[0];
  const float* r = (const float*)d_in[1];
  const unsigned char* seg = (const unsigned char*)d_in[2];
  const float* mask = (const float*)d_in[3];
  const float* wq = (const float*)d_in[4];
  const float* wk = (const float*)d_in[5];
  const float* wv = (const float*)d_in[6];
  const float* wr = (const float*)d_in[7];
  const float* wo = (const float*)d_in[8];
  const float* rwb = (const float*)d_in[9];
  const float* rrb = (const float*)d_in[10];
  const float* rsb = (const float*)d_in[11];
  const float* seg_embed = (const float*)d_in[12];
  const float* gamma = (const float*)d_in[13];
  const float* beta = (const float*)d_in[14];
  float* out = (float*)d_out;

  char* ws = (char*)d_ws;
  size_t off = 0;
  auto alloc = [&](size_t bytes) {
    size_t cur = off;
    off = (off + bytes + 255) & ~(size_t)255;
    return cur;
  };
  unsigned short* hb = (unsigned short*)(ws + alloc(2048 * 1024 * 2));
  unsigned short* rb = (unsigned short*)(ws + alloc(4096 * 1024 * 2));
  unsigned short* wq_t = (unsigned short*)(ws + alloc(1024 * 1024 * 2));
  unsigned short* wk_t = (unsigned short*)(ws + alloc(1024 * 1024 * 2));
  unsigned short* wv_t = (unsigned short*)(ws + alloc(1024 * 1024 * 2));
  unsigned short* wr_t = (unsigned short*)(ws + alloc(1024 * 1024 * 2));
  unsigned short* wo_b = (unsigned short*)(ws + alloc(1024 * 1024 * 2));
  unsigned short* qwb = (unsigned short*)(ws + alloc(2048 * 1024 * 2));
  unsigned short* qrb = (unsigned short*)(ws + alloc(2048 * 1024 * 2));
  unsigned short* khb = (unsigned short*)(ws + alloc(2048 * 1024 * 2));
  unsigned short* vhb = (unsigned short*)(ws + alloc(2048 * 1024 * 2));
  unsigned short* krhb = (unsigned short*)(ws + alloc(4096 * 1024 * 2));
  unsigned short* vTb = (unsigned short*)(ws + alloc(2048 * 1024 * 2));
  float* dvb = (float*)(ws + alloc(2048 * 16 * 4));
  unsigned int* segmask = (unsigned int*)(ws + alloc(2 * 1024 * 1024 * 4));
  unsigned short* avb = (unsigned short*)(ws + alloc(2048 * 1024 * 2));
  unsigned short* gout = (unsigned short*)(ws + alloc(2048 * 1024 * 2));
  unsigned short* part = (unsigned short*)(ws + alloc((size_t)2 * 32 * 1024 * 64 * 2));
  float* mlb = (float*)(ws + alloc((size_t)2 * 32 * 1024 * 4));
  (void)ws_size; (void)in_sizes; (void)n_in; (void)out_size;

  pre_kernel<<<15360, 256, 0, stream>>>(h, r, wo, wq, wk, wv, wr, seg, mask,
                                        hb, rb, wo_b, wq_t, wk_t, wv_t, wr_t, segmask);

  proj4_kernel<<<640, 512, 0, stream>>>(hb, rb, wq_t, wk_t, wv_t, wr_t, rwb, rrb, rsb,
                                        seg_embed, qwb, qrb, khb, vhb, krhb, dvb);

  transpose_v<<<dim3(16, 32), 256, 0, stream>>>(vhb, vTb);

  attn_kernel<<<dim3(32, 8, 2), 512, 0, stream>>>(qwb, qrb, khb, krhb, vTb,
                                                  dvb, segmask, part, mlb);
  combine_kernel<<<8192, 256, 0, stream>>>(part, mlb, avb);

  gemm64_out<<<256, 512, 0, stream>>>(avb, wo_b, gout);
  ln_kernel<<<2048, 256, 0, stream>>>(gout, h, gamma, beta, out);
}